// Round 15
// baseline (415.903 us; speedup 1.0000x reference)
//
#include <hip/hip_runtime.h>

// ---------------------------------------------------------------------------
// SpecDetrTransformerEncoderLayer on MI355X (gfx950)
// BS=4 NQ=12500 D=256 HEADS=8 LEVELS=2 POINTS=4 HD=32 D_FF=2048
// ---------------------------------------------------------------------------

#define NQv 12500
#define BSv 4
#define Dv  256
#define DFF 2048

typedef __attribute__((ext_vector_type(8))) __bf16 bf16x8;
typedef __attribute__((ext_vector_type(4))) float f32x4;

__device__ __forceinline__ ushort f32_to_bf16(float f) {
  unsigned u = __float_as_uint(f);
  u += 0x7FFFu + ((u >> 16) & 1u);
  return (ushort)(u >> 16);
}
__device__ __forceinline__ float bf16_to_f32(ushort u) {
  return __uint_as_float(((unsigned)u) << 16);
}

// ---------------- elementwise f32 -> bf16 ----------------------------------
__global__ __launch_bounds__(256) void conv_bf16_kernel(
    const float* __restrict__ in, ushort* __restrict__ out, int n4) {
  int i = blockIdx.x * 256 + threadIdx.x;
  if (i >= n4) return;
  float4 v = reinterpret_cast<const float4*>(in)[i];
  uint2 st;
  st.x = (unsigned)f32_to_bf16(v.x) | ((unsigned)f32_to_bf16(v.y) << 16);
  st.y = (unsigned)f32_to_bf16(v.z) | ((unsigned)f32_to_bf16(v.w) << 16);
  reinterpret_cast<uint2*>(out)[i] = st;
}

// ------- LDS-tiled transpose+convert: in[K][N] f32 -> out[N][K] bf16 -------
__global__ __launch_bounds__(256) void ttrans_kernel(
    const float* __restrict__ in, ushort* __restrict__ out, int K, int N) {
  __shared__ ushort tl[64][65];
  const int n0 = blockIdx.x * 64, k0 = blockIdx.y * 64;
  const int t = threadIdx.x;
#pragma unroll
  for (int i = 0; i < 16; ++i) {
    int idx = t + 256 * i;
    int r = idx >> 6, c = idx & 63;
    tl[r][c] = f32_to_bf16(in[(size_t)(k0 + r) * N + n0 + c]);
  }
  __syncthreads();
#pragma unroll
  for (int i = 0; i < 16; ++i) {
    int idx = t + 256 * i;
    int r = idx >> 6, c = idx & 63;
    out[(size_t)(n0 + r) * K + k0 + c] = tl[c][r];
  }
}

// ------------- concat-transpose of the 3 projection weights ----------------
__global__ __launch_bounds__(256) void build_wcat_kernel(
    const float* __restrict__ w_val, const float* __restrict__ w_off,
    const float* __restrict__ w_attn, const float* __restrict__ b_val,
    const float* __restrict__ b_off, const float* __restrict__ b_attn,
    ushort* __restrict__ wcat, float* __restrict__ bcat) {
  int i = blockIdx.x * 256 + threadIdx.x;
  if (i < 448 * 256) {
    int n = i >> 8, k = i & 255;
    float v = (n < 256) ? w_val[(size_t)k * 256 + n]
              : (n < 384) ? w_off[(size_t)k * 128 + (n - 256)]
                          : w_attn[(size_t)k * 64 + (n - 384)];
    wcat[i] = f32_to_bf16(v);
  }
  if (i < 512)
    bcat[i] = (i < 256) ? b_val[i] : (i < 384) ? b_off[i - 256]
              : (i < 448) ? b_attn[i - 384] : 0.f;
}

// ------------- pre-stage weights into [stage][chunk] order ------------------
template <int MODE>
__global__ __launch_bounds__(256) void stagefmt_kernel(
    const ushort* __restrict__ src, ushort* __restrict__ dst) {
  int i = blockIdx.x * 256 + threadIdx.x;
  int g = i >> 10, c = i & 1023;
  int srcrow, srck;
  if (MODE == 0) { srcrow = (g >> 2) * 128 + (c & 127); srck = (g & 3) * 64 + ((c >> 7) & 7) * 8; }
  if (MODE == 1) { srcrow = c & 255; srck = (g >> 2) * 128 + (g & 3) * 32 + ((c >> 8) & 3) * 8; }
  if (MODE == 2) { srcrow = c & 255; srck = g * 32 + ((c >> 8) & 3) * 8; }
  const int LD = (MODE == 1) ? 2048 : 256;
  *reinterpret_cast<uint4*>(dst + (size_t)i * 8) =
      *reinterpret_cast<const uint4*>(src + (size_t)srcrow * LD + srck);
}

// ---------------- 2-phase double-buffered bf16 MFMA GEMM -------------------
// Bijective XCD-chunked block swizzle (m204) for A-tile L2 locality.
#define TBM 128
#define TBN 128
#define TBK 32

template <int RELU, int NMASK, int SPLIT>
__global__ __launch_bounds__(256) void gemm128_kernel(
    const ushort* __restrict__ A, const ushort* __restrict__ Bt,
    const float* __restrict__ bias, ushort* __restrict__ C,
    ushort* __restrict__ C2,
    int M, int K, int ldc, int Nreal) {
  __shared__ ushort lds[4][TBM * TBK];

  const int t = threadIdx.x;
  const int wid = t >> 6, lane = t & 63;
  const int wr = wid >> 1, wc = wid & 1;

  // XCD-bijective remap: consecutive wgid within an XCD chunk share A-tiles
  const int nwg = gridDim.x * gridDim.y;
  const int lbid = blockIdx.y * gridDim.x + blockIdx.x;
  const int q = nwg >> 3, r = nwg & 7;
  const int xcd = lbid & 7, li = lbid >> 3;
  const int wgid = (xcd < r ? xcd * (q + 1) : r * (q + 1) + (xcd - r) * q) + li;
  const int m0 = (wgid / gridDim.x) * TBM;
  const int n0 = (wgid % gridDim.x) * TBN;

  int srowA[2], srowB[2], gsl[2];
#pragma unroll
  for (int i = 0; i < 2; i++) {
    int row = i * 64 + (t >> 2);
    int ar = m0 + row;
    srowA[i] = (ar < M) ? ar : (M - 1);
    srowB[i] = n0 + row;
    gsl[i] = ((t & 3) ^ ((row >> 1) & 3)) * 8;
  }

  f32x4 acc[4][4] = {};
  const int nt = K / TBK;
  int cur = 0;

#pragma unroll
  for (int i = 0; i < 2; i++) {
    const int ldsoff = (i * 256 + wid * 64) * 8;
    __builtin_amdgcn_global_load_lds(
        (const __attribute__((address_space(1))) void*)(A + (size_t)srowA[i] * K + gsl[i]),
        (__attribute__((address_space(3))) void*)(lds[0] + ldsoff), 16, 0, 0);
    __builtin_amdgcn_global_load_lds(
        (const __attribute__((address_space(1))) void*)(Bt + (size_t)srowB[i] * K + gsl[i]),
        (__attribute__((address_space(3))) void*)(lds[1] + ldsoff), 16, 0, 0);
  }
  __syncthreads();

  const int rl = lane & 15, kh = lane >> 4;
  for (int tk = 0; tk < nt; ++tk) {
    if (tk + 1 < nt) {
      const int k0 = (tk + 1) * TBK;
      const int nb = (cur ^ 1) * 2;
#pragma unroll
      for (int i = 0; i < 2; i++) {
        const int ldsoff = (i * 256 + wid * 64) * 8;
        __builtin_amdgcn_global_load_lds(
            (const __attribute__((address_space(1))) void*)(A + (size_t)srowA[i] * K + k0 + gsl[i]),
            (__attribute__((address_space(3))) void*)(lds[nb] + ldsoff), 16, 0, 0);
        __builtin_amdgcn_global_load_lds(
            (const __attribute__((address_space(1))) void*)(Bt + (size_t)srowB[i] * K + k0 + gsl[i]),
            (__attribute__((address_space(3))) void*)(lds[nb + 1] + ldsoff), 16, 0, 0);
      }
    }
    {
      const ushort* As = lds[cur * 2];
      const ushort* Bs = lds[cur * 2 + 1];
      bf16x8 afr[4], bfr[4];
#pragma unroll
      for (int ni = 0; ni < 4; ni++) {
        int rowb = wc * 64 + ni * 16 + rl;
        int p = kh ^ ((rowb >> 1) & 3);
        bfr[ni] = *reinterpret_cast<const bf16x8*>(Bs + rowb * 32 + p * 8);
      }
#pragma unroll
      for (int mi = 0; mi < 4; mi++) {
        int rowa = wr * 64 + mi * 16 + rl;
        int p = kh ^ ((rowa >> 1) & 3);
        afr[mi] = *reinterpret_cast<const bf16x8*>(As + rowa * 32 + p * 8);
      }
#pragma unroll
      for (int mi = 0; mi < 4; mi++)
#pragma unroll
        for (int ni = 0; ni < 4; ni++)
          acc[mi][ni] = __builtin_amdgcn_mfma_f32_16x16x32_bf16(afr[mi], bfr[ni], acc[mi][ni], 0, 0, 0);
    }
    __syncthreads();
    cur ^= 1;
  }

  ushort* ldsC = lds[0];
  const int rgrp = lane >> 4, cl = lane & 15;
#pragma unroll
  for (int pass = 0; pass < 2; ++pass) {
    if (wr == pass) {
#pragma unroll
      for (int mi = 0; mi < 4; mi++) {
#pragma unroll
        for (int ni = 0; ni < 4; ni++) {
          int col = wc * 64 + ni * 16 + cl;
          float bv = bias[n0 + col];
#pragma unroll
          for (int r = 0; r < 4; r++) {
            int rloc = mi * 16 + rgrp * 4 + r;
            float v = acc[mi][ni][r] + bv;
            if (RELU) v = fmaxf(v, 0.f);
            ldsC[rloc * 132 + col] = f32_to_bf16(v);
          }
        }
      }
    }
    __syncthreads();
    {
      int rloc = t >> 2;
      int row = m0 + pass * 64 + rloc;
      if (row < M) {
#pragma unroll
        for (int j = 0; j < 4; j++) {
          int col = (t & 3) * 32 + j * 8;
          uint4 v = *reinterpret_cast<const uint4*>(ldsC + rloc * 132 + col);
          if (SPLIT) {
            int gcol = n0 + col;
            if (gcol < 256)
              *reinterpret_cast<uint4*>(C + (size_t)row * 256 + gcol) = v;
            else if (gcol < 448)
              *reinterpret_cast<uint4*>(C2 + (size_t)row * 192 + (gcol - 256)) = v;
          } else if (!NMASK || n0 + col < Nreal) {
            *reinterpret_cast<uint4*>(C + (size_t)row * ldc + n0 + col) = v;
          }
        }
      }
    }
    __syncthreads();
  }
}

// ---------------- fused out-proj + bias + residual + LN0 -------------------
// samp frag-order in, wqf pre-staged, xb written via LDS repack (coalesced).
__global__ __launch_bounds__(256, 2) void outproj_ln0_kernel(
    const ushort* __restrict__ samp,  // frag-order, 16384 us per 64-row block
    const ushort* __restrict__ wqf,   // 8 stages x 8192 us
    const float* __restrict__ bias,   // [256]
    const float* __restrict__ query,  // [M][256] f32
    const float* __restrict__ g0, const float* __restrict__ be0,
    ushort* __restrict__ xb,          // ffn frag-order, 32768 us per 128-row blk
    int M) {
  __shared__ ushort lds_all[32768];          // 64 KB
  ushort* As = lds_all;                      // 16384 us, frag-order
  ushort* ring0 = lds_all + 16384;           // 2 x 8192 us

  const int t = threadIdx.x;
  const int wv = t >> 6;
  const int lane = t & 63;
  const int rl = lane & 15, kq = lane >> 4;
  const int cl = lane & 15, g4 = lane >> 4;
  const int m0 = blockIdx.x * 64;

  ushort* ring[2] = {ring0, ring0 + 8192};

  auto issueB = [&](int j, ushort* dst) {
#pragma unroll
    for (int ii = 0; ii < 4; ++ii) {
      int c = t + 256 * ii;
      __builtin_amdgcn_global_load_lds(
          (const __attribute__((address_space(1))) void*)(wqf + (size_t)j * 8192 + (size_t)c * 8),
          (__attribute__((address_space(3))) void*)(dst + (size_t)c * 8), 16, 0, 0);
    }
  };

#pragma unroll
  for (int ii = 0; ii < 8; ++ii) {
    int c = t + 256 * ii;
    __builtin_amdgcn_global_load_lds(
        (const __attribute__((address_space(1))) void*)(
            samp + (size_t)blockIdx.x * 16384 + (size_t)c * 8),
        (__attribute__((address_space(3))) void*)(As + (size_t)c * 8), 16, 0, 0);
  }
  issueB(0, ring[0]);
  __syncthreads();

  f32x4 accF[4][4] = {};
  int cur = 0;

#pragma unroll
  for (int j = 0; j < 8; ++j) {
    if (j + 1 < 8) issueB(j + 1, ring[cur ^ 1]);
    const ushort* Bs = ring[cur];
    bf16x8 afr[4], bfr[4];
#pragma unroll
    for (int mi = 0; mi < 4; mi++)
      afr[mi] = *reinterpret_cast<const bf16x8*>(As + (j * 4 + kq) * 512 + (mi * 16 + rl) * 8);
#pragma unroll
    for (int ni = 0; ni < 4; ni++)
      bfr[ni] = *reinterpret_cast<const bf16x8*>(Bs + kq * 2048 + (wv * 64 + ni * 16 + rl) * 8);
    __builtin_amdgcn_s_setprio(1);
#pragma unroll
    for (int mi = 0; mi < 4; mi++)
#pragma unroll
      for (int ni = 0; ni < 4; ni++)
        accF[mi][ni] = __builtin_amdgcn_mfma_f32_16x16x32_bf16(afr[mi], bfr[ni], accF[mi][ni], 0, 0, 0);
    __builtin_amdgcn_s_setprio(0);
    __syncthreads();
    cur ^= 1;
  }

  float* ptab = (float*)ring0;
  float* mtab = (float*)(ring0 + 2048);

  float bc[4], gc[4], bec[4];
#pragma unroll
  for (int ni = 0; ni < 4; ni++) {
    int col = wv * 64 + ni * 16 + cl;
    bc[ni] = bias[col]; gc[ni] = g0[col]; bec[ni] = be0[col];
  }
#pragma unroll
  for (int mi = 0; mi < 4; mi++) {
#pragma unroll
    for (int ni = 0; ni < 4; ni++) {
      int col = wv * 64 + ni * 16 + cl;
#pragma unroll
      for (int r = 0; r < 4; r++) {
        int row = mi * 16 + g4 * 4 + r;
        int qrow = m0 + row; qrow = (qrow < M) ? qrow : (M - 1);
        accF[mi][ni][r] += bc[ni] + query[(size_t)qrow * 256 + col];
      }
    }
  }
#pragma unroll
  for (int mi = 0; mi < 4; mi++) {
#pragma unroll
    for (int r = 0; r < 4; r++) {
      float s = accF[mi][0][r] + accF[mi][1][r] + accF[mi][2][r] + accF[mi][3][r];
      float sq = accF[mi][0][r] * accF[mi][0][r] + accF[mi][1][r] * accF[mi][1][r] +
                 accF[mi][2][r] * accF[mi][2][r] + accF[mi][3][r] * accF[mi][3][r];
#pragma unroll
      for (int o = 1; o < 16; o <<= 1) {
        s += __shfl_xor(s, o, 64);
        sq += __shfl_xor(sq, o, 64);
      }
      if (cl == 0) {
        int row = mi * 16 + g4 * 4 + r;
        ptab[(row * 4 + wv) * 2 + 0] = s;
        ptab[(row * 4 + wv) * 2 + 1] = sq;
      }
    }
  }
  __syncthreads();
  {
    int row = t >> 2, part = t & 3;
    float s = ptab[(row * 4 + part) * 2 + 0];
    float sq = ptab[(row * 4 + part) * 2 + 1];
    s += __shfl_xor(s, 1, 64);  sq += __shfl_xor(sq, 1, 64);
    s += __shfl_xor(s, 2, 64);  sq += __shfl_xor(sq, 2, 64);
    if (part == 0) {
      float mean = s * (1.f / 256.f);
      float var = sq * (1.f / 256.f) - mean * mean;
      mtab[row * 2 + 0] = mean;
      mtab[row * 2 + 1] = rsqrtf(var + 1e-5f);
    }
  }
  __syncthreads();
  // LN -> As in frag-order (LDS), then coalesced linear copy to xb
#pragma unroll
  for (int mi = 0; mi < 4; mi++) {
#pragma unroll
    for (int r = 0; r < 4; r++) {
      int row = mi * 16 + g4 * 4 + r;
      float2 ms = *reinterpret_cast<const float2*>(mtab + row * 2);
#pragma unroll
      for (int ni = 0; ni < 4; ni++) {
        int col = wv * 64 + ni * 16 + cl;
        As[(col >> 3) * 512 + row * 8 + (col & 7)] =
            f32_to_bf16((accF[mi][ni][r] - ms.x) * ms.y * gc[ni] + bec[ni]);
      }
    }
  }
  __syncthreads();
  {
    const size_t base128 = (size_t)(blockIdx.x >> 1) * 32768 + (size_t)(blockIdx.x & 1) * 512;
#pragma unroll
    for (int ii = 0; ii < 8; ++ii) {
      int c = t + 256 * ii;
      int s = c >> 6, rl2 = c & 63;
      if (m0 + rl2 < M)
        *reinterpret_cast<uint4*>(xb + base128 + (size_t)s * 1024 + (size_t)rl2 * 8) =
            *reinterpret_cast<const uint4*>(As + (size_t)c * 8);
    }
  }
}

// ---------------- fused FFN1+ReLU+FFN2+residual+LN1 ------------------------
// (unchanged from R14: frag-order LDS, pre-staged weights, counted vmcnt)
__global__ __launch_bounds__(512, 1) void ffn_ln_fused_kernel(
    const ushort* __restrict__ xb, const ushort* __restrict__ w1f,
    const float* __restrict__ b1, const ushort* __restrict__ w2f,
    const float* __restrict__ b2, const float* __restrict__ g1,
    const float* __restrict__ be1, float* __restrict__ out, int M) {
  __shared__ ushort lds_all[73856];            // 147.7 KB
  ushort* As = lds_all;                        // 32768 us
  ushort* Hs = lds_all + 32768;                // 16512 us (16 planes x 1032)
  ushort* stg0 = lds_all + 49280;              // 3 x 8192 us

  const int t = threadIdx.x;
  const int wv = t >> 6;
  const int wm = wv >> 2;
  const int wn = wv & 3;
  const int lane = t & 63;
  const int rl = lane & 15, kq = lane >> 4;
  const int cl = lane & 15, g4 = lane >> 4;
  const int m0 = blockIdx.x * 128;

  auto stg = [&](int i) { return stg0 + i * 8192; };

  auto issueB1 = [&](int p, int j, ushort* dst) {
    const ushort* src = w1f + (size_t)(p * 4 + j) * 8192;
#pragma unroll
    for (int ii = 0; ii < 2; ++ii) {
      int c = t + 512 * ii;
      __builtin_amdgcn_global_load_lds(
          (const __attribute__((address_space(1))) void*)(src + (size_t)c * 8),
          (__attribute__((address_space(3))) void*)(dst + (size_t)c * 8), 16, 0, 0);
    }
  };
  auto issueB2 = [&](int p, int tt, ushort* dst) {
    const ushort* src = w2f + (size_t)(p * 4 + tt) * 8192;
#pragma unroll
    for (int ii = 0; ii < 2; ++ii) {
      int c = t + 512 * ii;
      __builtin_amdgcn_global_load_lds(
          (const __attribute__((address_space(1))) void*)(src + (size_t)c * 8),
          (__attribute__((address_space(3))) void*)(dst + (size_t)c * 8), 16, 0, 0);
    }
  };

#pragma unroll
  for (int ii = 0; ii < 8; ++ii) {
    int c = t + 512 * ii;
    __builtin_amdgcn_global_load_lds(
        (const __attribute__((address_space(1))) void*)(
            xb + (size_t)blockIdx.x * 32768 + (size_t)c * 8),
        (__attribute__((address_space(3))) void*)(As + (size_t)c * 8), 16, 0, 0);
  }
  issueB1(0, 0, stg(0));
  issueB1(0, 1, stg(1));
  asm volatile("s_waitcnt vmcnt(2)" ::: "memory");
  __builtin_amdgcn_s_barrier();

  f32x4 acc1[4][2] = {};
  f32x4 accF[4][4] = {};
  int cur = 0;

  for (int p = 0; p < 16; ++p) {
#pragma unroll
    for (int j = 0; j < 8; ++j) {
      int tgt = cur + 2; if (tgt >= 3) tgt -= 3;
      if (j <= 5) {
        const int j2 = j + 2;
        const int p2 = p + (j2 >> 3);
        if ((j2 & 7) < 4) issueB1(p2, j2 & 3, stg(tgt));
        else issueB2(p2, (j2 & 7) - 4, stg(tgt));
        asm volatile("s_waitcnt vmcnt(4) lgkmcnt(0)" ::: "memory");
      } else if (p < 15) {
        const int j2m = (j + 2) & 7;
        issueB1(p + 1, j2m, stg(tgt));
        asm volatile("s_waitcnt vmcnt(4) lgkmcnt(0)" ::: "memory");
      } else if (j == 6) {
        asm volatile("s_waitcnt vmcnt(2) lgkmcnt(0)" ::: "memory");
      } else {
        asm volatile("s_waitcnt vmcnt(0) lgkmcnt(0)" ::: "memory");
      }
      __builtin_amdgcn_s_barrier();
      __builtin_amdgcn_sched_barrier(0);

      const ushort* Bs = stg(cur);
      if (j < 4) {
        __builtin_amdgcn_s_setprio(1);
#pragma unroll
        for (int kk = 0; kk < 2; ++kk) {
          bf16x8 afr[4], bfr[2];
          const int slotA = j * 8 + kk * 4 + kq;
#pragma unroll
          for (int mi = 0; mi < 4; mi++)
            afr[mi] = *reinterpret_cast<const bf16x8*>(
                As + slotA * 1024 + (wm * 64 + mi * 16 + rl) * 8);
          const int slotB = kk * 4 + kq;
#pragma unroll
          for (int ni = 0; ni < 2; ni++)
            bfr[ni] = *reinterpret_cast<const bf16x8*>(
                Bs + slotB * 1024 + (wn * 32 + ni * 16 + rl) * 8);
#pragma unroll
          for (int mi = 0; mi < 4; mi++)
#pragma unroll
            for (int ni = 0; ni < 2; ni++)
              acc1[mi][ni] = __builtin_amdgcn_mfma_f32_16x16x32_bf16(afr[mi], bfr[ni], acc1[mi][ni], 0, 0, 0);
        }
        __builtin_amdgcn_s_setprio(0);
        if (j == 3) {
#pragma unroll
          for (int ni = 0; ni < 2; ni++) {
            int col = wn * 32 + ni * 16 + cl;
            float b1v = b1[p * 128 + col];
            const int s = col >> 3, w8 = col & 7;
#pragma unroll
            for (int mi = 0; mi < 4; mi++) {
#pragma unroll
              for (int r = 0; r < 4; r++) {
                int row = wm * 64 + mi * 16 + g4 * 4 + r;
                Hs[s * 1032 + row * 8 + w8] = f32_to_bf16(fmaxf(acc1[mi][ni][r] + b1v, 0.f));
              }
            }
          }
#pragma unroll
          for (int mi = 0; mi < 4; mi++)
#pragma unroll
            for (int ni = 0; ni < 2; ni++)
              acc1[mi][ni] = (f32x4){0.f, 0.f, 0.f, 0.f};
        }
      } else {
        const int tt = j - 4;
        bf16x8 a2f[4], b2f[4];
#pragma unroll
        for (int mi = 0; mi < 4; mi++)
          a2f[mi] = *reinterpret_cast<const bf16x8*>(
              Hs + (tt * 4 + kq) * 1032 + (wm * 64 + mi * 16 + rl) * 8);
#pragma unroll
        for (int ni = 0; ni < 4; ni++)
          b2f[ni] = *reinterpret_cast<const bf16x8*>(
              Bs + kq * 2048 + (wn * 64 + ni * 16 + rl) * 8);
        __builtin_amdgcn_s_setprio(1);
#pragma unroll
        for (int mi = 0; mi < 4; mi++)
#pragma unroll
          for (int ni = 0; ni < 4; ni++)
            accF[mi][ni] = __builtin_amdgcn_mfma_f32_16x16x32_bf16(a2f[mi], b2f[ni], accF[mi][ni], 0, 0, 0);
        __builtin_amdgcn_s_setprio(0);
      }
      cur = cur + 1; if (cur >= 3) cur -= 3;
    }
  }

  float* ptab = (float*)stg0;
  float* mtab = (float*)(stg0 + 2048);

  float b2c[4], g1c[4], bec[4];
#pragma unroll
  for (int ni = 0; ni < 4; ni++) {
    int col = wn * 64 + ni * 16 + cl;
    b2c[ni] = b2[col]; g1c[ni] = g1[col]; bec[ni] = be1[col];
  }
#pragma unroll
  for (int mi = 0; mi < 4; mi++) {
#pragma unroll
    for (int ni = 0; ni < 4; ni++) {
      int col = wn * 64 + ni * 16 + cl;
#pragma unroll
      for (int r = 0; r < 4; r++) {
        int row = wm * 64 + mi * 16 + g4 * 4 + r;
        ushort xv = As[(col >> 3) * 1024 + row * 8 + (col & 7)];
        accF[mi][ni][r] += b2c[ni] + bf16_to_f32(xv);
      }
    }
  }
#pragma unroll
  for (int mi = 0; mi < 4; mi++) {
#pragma unroll
    for (int r = 0; r < 4; r++) {
      float s = accF[mi][0][r] + accF[mi][1][r] + accF[mi][2][r] + accF[mi][3][r];
      float sq = accF[mi][0][r] * accF[mi][0][r] + accF[mi][1][r] * accF[mi][1][r] +
                 accF[mi][2][r] * accF[mi][2][r] + accF[mi][3][r] * accF[mi][3][r];
#pragma unroll
      for (int o = 1; o < 16; o <<= 1) {
        s += __shfl_xor(s, o, 64);
        sq += __shfl_xor(sq, o, 64);
      }
      if (cl == 0) {
        int row = wm * 64 + mi * 16 + g4 * 4 + r;
        ptab[(row * 4 + wn) * 2 + 0] = s;
        ptab[(row * 4 + wn) * 2 + 1] = sq;
      }
    }
  }
  __syncthreads();
  {
    int row = t >> 2, part = t & 3;
    float s = ptab[(row * 4 + part) * 2 + 0];
    float sq = ptab[(row * 4 + part) * 2 + 1];
    s += __shfl_xor(s, 1, 64);  sq += __shfl_xor(sq, 1, 64);
    s += __shfl_xor(s, 2, 64);  sq += __shfl_xor(sq, 2, 64);
    if (part == 0) {
      float mean = s * (1.f / 256.f);
      float var = sq * (1.f / 256.f) - mean * mean;
      mtab[row * 2 + 0] = mean;
      mtab[row * 2 + 1] = rsqrtf(var + 1e-5f);
    }
  }
  __syncthreads();
#pragma unroll
  for (int mi = 0; mi < 4; mi++) {
#pragma unroll
    for (int r = 0; r < 4; r++) {
      int row = wm * 64 + mi * 16 + g4 * 4 + r;
      float2 ms = *reinterpret_cast<const float2*>(mtab + row * 2);
      int grow = m0 + row;
      if (grow < M) {
#pragma unroll
        for (int ni = 0; ni < 4; ni++) {
          int col = wn * 64 + ni * 16 + cl;
          out[(size_t)grow * 256 + col] = (accF[mi][ni][r] - ms.x) * ms.y * g1c[ni] + bec[ni];
        }
      }
    }
  }
}

// ---------------- deformable attention sampling ----------------------------
// Thread map: (plane s = h*4+c, row) so each wave writes one plane's 64 rows
// = 1 KB contiguous frag-order store. Per-thread softmax (R12: redundancy is
// free; kernel is gather-latency-bound).
__global__ __launch_bounds__(256) void deform_attn_kernel(
    const ushort* __restrict__ val,  // [R][256] bf16
    const ushort* __restrict__ oa,   // [R][192] bf16: off 0..127 | aw 128..191
    const float* __restrict__ refp,  // [R][4]
    ushort* __restrict__ out,        // frag-order, 16384 us per 64-row block
    int R) {
  int g = blockIdx.x * 256 + threadIdx.x;
  int b64 = g >> 11;
  int idx = g & 2047;
  int s = idx >> 6;          // 0..31
  int rl = idx & 63;
  int h = s >> 2, c = s & 3;
  int row = b64 * 64 + rl;
  if (row >= R) return;
  int bl = row / NQv;

  const ushort* orow = oa + (size_t)row * 192;

  // softmax over head h's 8 logits (per-thread)
  ushort lg[8];
  *reinterpret_cast<uint4*>(lg) = *reinterpret_cast<const uint4*>(orow + 128 + h * 8);
  float e[8], mx = -1e30f;
#pragma unroll
  for (int i = 0; i < 8; i++) { e[i] = bf16_to_f32(lg[i]); mx = fmaxf(mx, e[i]); }
  float sm = 0.f;
#pragma unroll
  for (int i = 0; i < 8; i++) { e[i] = __expf(e[i] - mx); sm += e[i]; }
  float inv = 1.f / sm;

  ushort ofr[16];
  *reinterpret_cast<uint4*>(ofr)     = *reinterpret_cast<const uint4*>(orow + h * 16);
  *reinterpret_cast<uint4*>(ofr + 8) = *reinterpret_cast<const uint4*>(orow + h * 16 + 8);
  float4 rp = *reinterpret_cast<const float4*>(refp + (size_t)row * 4);

  float acc8[8] = {};
#pragma unroll
  for (int p = 0; p < 8; ++p) {
    const int l = p >> 2;
    const float Wl = l ? 50.f : 100.f;
    const int W = l ? 50 : 100, H = W;
    float fx = (l ? rp.z : rp.x) * Wl - 0.5f;
    float fy = (l ? rp.w : rp.y) * Wl - 0.5f;
    float x = fx + bf16_to_f32(ofr[p * 2 + 0]);
    float y = fy + bf16_to_f32(ofr[p * 2 + 1]);
    float w = e[p] * inv;
    const ushort* vbase = val + ((size_t)bl * NQv + (l ? 10000 : 0)) * 256 + h * 32 + c * 8;
    float x0f = floorf(x), y0f = floorf(y);
    float wx1 = x - x0f, wy1 = y - y0f;
    float wx0 = 1.f - wx1, wy0 = 1.f - wy1;
    int x0 = (int)x0f, y0 = (int)y0f;
    float cw[4] = {w * wx0 * wy0, w * wx1 * wy0, w * wx0 * wy1, w * wx1 * wy1};
    int cx[4] = {x0, x0 + 1, x0, x0 + 1};
    int cy[4] = {y0, y0, y0 + 1, y0 + 1};
#pragma unroll
    for (int cc = 0; cc < 4; cc++) {
      int xi = cx[cc], yi = cy[cc];
      if (xi >= 0 && xi < W && yi >= 0 && yi < H) {
        ushort vr[8];
        *reinterpret_cast<uint4*>(vr) =
            *reinterpret_cast<const uint4*>(vbase + (size_t)(yi * W + xi) * 256);
        float ww = cw[cc];
#pragma unroll
        for (int j = 0; j < 8; j++) acc8[j] += ww * bf16_to_f32(vr[j]);
      }
    }
  }

  ushort st[8];
#pragma unroll
  for (int j = 0; j < 8; j++) st[j] = f32_to_bf16(acc8[j]);
  *reinterpret_cast<uint4*>(out + (size_t)b64 * 16384 + (size_t)s * 512 + (size_t)rl * 8) =
      *reinterpret_cast<uint4*>(st);
}

// ---------------------------------------------------------------------------
extern "C" void kernel_launch(void* const* d_in, const int* in_sizes, int n_in,
                              void* d_out, int out_size, void* d_ws, size_t ws_size,
                              hipStream_t stream) {
  const float* query  = (const float*)d_in[0];
  const float* refp   = (const float*)d_in[1];
  const float* w_off  = (const float*)d_in[2];
  const float* b_off  = (const float*)d_in[3];
  const float* w_attn = (const float*)d_in[4];
  const float* b_attn = (const float*)d_in[5];
  const float* w_val  = (const float*)d_in[6];
  const float* b_val  = (const float*)d_in[7];
  const float* w_out  = (const float*)d_in[8];
  const float* b_out  = (const float*)d_in[9];
  const float* w1     = (const float*)d_in[10];
  const float* b1     = (const float*)d_in[11];
  const float* w2     = (const float*)d_in[12];
  const float* b2     = (const float*)d_in[13];
  const float* ln0g   = (const float*)d_in[14];
  const float* ln0b   = (const float*)d_in[15];
  const float* ln1g   = (const float*)d_in[16];
  const float* ln1b   = (const float*)d_in[17];
  float* outp = (float*)d_out;

  char* ws = (char*)d_ws;
  size_t woff = 0;
  auto walloc = [&](size_t bytes) { size_t r = woff; woff += (bytes + 255) & ~(size_t)255; return r; };
  ushort* wcat = (ushort*)(ws + walloc((size_t)512 * 256 * 2));
  float*  bcat = (float*)(ws + walloc(512 * 4));
  ushort* wqt  = (ushort*)(ws + walloc((size_t)256 * 256 * 2));
  ushort* w1t  = (ushort*)(ws + walloc((size_t)DFF * 256 * 2));
  ushort* w2t  = (ushort*)(ws + walloc((size_t)256 * DFF * 2));
  ushort* wqf  = (ushort*)(ws + walloc((size_t)8 * 8192 * 2));
  ushort* w1f  = (ushort*)(ws + walloc((size_t)64 * 8192 * 2));
  ushort* w2f  = (ushort*)(ws + walloc((size_t)64 * 8192 * 2));
  char* arena = ws + woff;
  size_t arena_sz = (ws_size > woff) ? (ws_size - woff) : 0;

  int nb = ((size_t)BSv * NQv * 1920 + (4u << 20) <= arena_sz) ? BSv : 1;
  const int R = nb * NQv;
  const size_t xbsz = (size_t)((R + 127) / 128) * 65536;   // frag-order xb bytes
  ushort* qb   = (ushort*)arena;                           // row-major, then xb
  ushort* valb = (ushort*)(arena + xbsz);
  ushort* oab  = (ushort*)(arena + xbsz + (size_t)R * 512);
  ushort* samp = (ushort*)(arena + xbsz + (size_t)R * 512 + (size_t)R * 384);
  ushort* xb   = qb;

  build_wcat_kernel<<<dim3(448), dim3(256), 0, stream>>>(
      w_val, w_off, w_attn, b_val, b_off, b_attn, wcat, bcat);
  ttrans_kernel<<<dim3(4, 4), dim3(256), 0, stream>>>(w_out, wqt, Dv, Dv);
  ttrans_kernel<<<dim3(DFF / 64, 4), dim3(256), 0, stream>>>(w1, w1t, Dv, DFF);
  ttrans_kernel<<<dim3(4, DFF / 64), dim3(256), 0, stream>>>(w2, w2t, DFF, Dv);
  stagefmt_kernel<2><<<dim3(32), dim3(256), 0, stream>>>(wqt, wqf);
  stagefmt_kernel<0><<<dim3(256), dim3(256), 0, stream>>>(w1t, w1f);
  stagefmt_kernel<1><<<dim3(256), dim3(256), 0, stream>>>(w2t, w2f);

  const int MT = (R + TBM - 1) / TBM;

  for (int c = 0; c < BSv / nb; c++) {
    const int row0 = c * R;
    const float* qrow = query + (size_t)row0 * Dv;

    conv_bf16_kernel<<<dim3((R * 64 + 255) / 256), dim3(256), 0, stream>>>(qrow, qb, R * 64);

    gemm128_kernel<0, 1, 1><<<dim3(4, MT), dim3(256), 0, stream>>>(
        qb, wcat, bcat, valb, oab, R, Dv, 448, 448);

    deform_attn_kernel<<<dim3(((R + 63) / 64) * 8), dim3(256), 0, stream>>>(
        valb, oab, refp + (size_t)row0 * 4, samp, R);

    outproj_ln0_kernel<<<dim3((R + 63) / 64), dim3(256), 0, stream>>>(
        samp, wqf, b_out, qrow, ln0g, ln0b, xb, R);

    ffn_ln_fused_kernel<<<dim3((R + 127) / 128), dim3(512), 0, stream>>>(
        xb, w1f, b1, w2f, b2, ln1g, ln1b, outp + (size_t)row0 * 256, R);
  }
}

// Round 16
// 323.511 us; speedup vs baseline: 1.2856x; 1.2856x over previous
//
#include <hip/hip_runtime.h>

// ---------------------------------------------------------------------------
// SpecDetrTransformerEncoderLayer on MI355X (gfx950)
// BS=4 NQ=12500 D=256 HEADS=8 LEVELS=2 POINTS=4 HD=32 D_FF=2048
// ---------------------------------------------------------------------------

#define NQv 12500
#define BSv 4
#define Dv  256
#define DFF 2048

typedef __attribute__((ext_vector_type(8))) __bf16 bf16x8;
typedef __attribute__((ext_vector_type(4))) float f32x4;

__device__ __forceinline__ ushort f32_to_bf16(float f) {
  unsigned u = __float_as_uint(f);
  u += 0x7FFFu + ((u >> 16) & 1u);
  return (ushort)(u >> 16);
}
__device__ __forceinline__ float bf16_to_f32(ushort u) {
  return __uint_as_float(((unsigned)u) << 16);
}

// ---------------- elementwise f32 -> bf16 ----------------------------------
__global__ __launch_bounds__(256) void conv_bf16_kernel(
    const float* __restrict__ in, ushort* __restrict__ out, int n4) {
  int i = blockIdx.x * 256 + threadIdx.x;
  if (i >= n4) return;
  float4 v = reinterpret_cast<const float4*>(in)[i];
  uint2 st;
  st.x = (unsigned)f32_to_bf16(v.x) | ((unsigned)f32_to_bf16(v.y) << 16);
  st.y = (unsigned)f32_to_bf16(v.z) | ((unsigned)f32_to_bf16(v.w) << 16);
  reinterpret_cast<uint2*>(out)[i] = st;
}

// ------- LDS-tiled transpose+convert: in[K][N] f32 -> out[N][K] bf16 -------
__global__ __launch_bounds__(256) void ttrans_kernel(
    const float* __restrict__ in, ushort* __restrict__ out, int K, int N) {
  __shared__ ushort tl[64][65];
  const int n0 = blockIdx.x * 64, k0 = blockIdx.y * 64;
  const int t = threadIdx.x;
#pragma unroll
  for (int i = 0; i < 16; ++i) {
    int idx = t + 256 * i;
    int r = idx >> 6, c = idx & 63;
    tl[r][c] = f32_to_bf16(in[(size_t)(k0 + r) * N + n0 + c]);
  }
  __syncthreads();
#pragma unroll
  for (int i = 0; i < 16; ++i) {
    int idx = t + 256 * i;
    int r = idx >> 6, c = idx & 63;
    out[(size_t)(n0 + r) * K + k0 + c] = tl[c][r];
  }
}

// ------------- concat-transpose of the 3 projection weights ----------------
__global__ __launch_bounds__(256) void build_wcat_kernel(
    const float* __restrict__ w_val, const float* __restrict__ w_off,
    const float* __restrict__ w_attn, const float* __restrict__ b_val,
    const float* __restrict__ b_off, const float* __restrict__ b_attn,
    ushort* __restrict__ wcat, float* __restrict__ bcat) {
  int i = blockIdx.x * 256 + threadIdx.x;
  if (i < 448 * 256) {
    int n = i >> 8, k = i & 255;
    float v = (n < 256) ? w_val[(size_t)k * 256 + n]
              : (n < 384) ? w_off[(size_t)k * 128 + (n - 256)]
                          : w_attn[(size_t)k * 64 + (n - 384)];
    wcat[i] = f32_to_bf16(v);
  }
  if (i < 512)
    bcat[i] = (i < 256) ? b_val[i] : (i < 384) ? b_off[i - 256]
              : (i < 448) ? b_attn[i - 384] : 0.f;
}

// ------------- pre-stage weights into [stage][chunk] order ------------------
template <int MODE>
__global__ __launch_bounds__(256) void stagefmt_kernel(
    const ushort* __restrict__ src, ushort* __restrict__ dst) {
  int i = blockIdx.x * 256 + threadIdx.x;
  int g = i >> 10, c = i & 1023;
  int srcrow, srck;
  if (MODE == 0) { srcrow = (g >> 2) * 128 + (c & 127); srck = (g & 3) * 64 + ((c >> 7) & 7) * 8; }
  if (MODE == 1) { srcrow = c & 255; srck = (g >> 2) * 128 + (g & 3) * 32 + ((c >> 8) & 3) * 8; }
  if (MODE == 2) { srcrow = c & 255; srck = g * 32 + ((c >> 8) & 3) * 8; }
  const int LD = (MODE == 1) ? 2048 : 256;
  *reinterpret_cast<uint4*>(dst + (size_t)i * 8) =
      *reinterpret_cast<const uint4*>(src + (size_t)srcrow * LD + srck);
}

// ---------------- 2-phase double-buffered bf16 MFMA GEMM -------------------
#define TBM 128
#define TBN 128
#define TBK 32

template <int RELU, int NMASK, int SPLIT>
__global__ __launch_bounds__(256) void gemm128_kernel(
    const ushort* __restrict__ A, const ushort* __restrict__ Bt,
    const float* __restrict__ bias, ushort* __restrict__ C,
    ushort* __restrict__ C2,
    int M, int K, int ldc, int Nreal) {
  __shared__ ushort lds[4][TBM * TBK];

  const int t = threadIdx.x;
  const int wid = t >> 6, lane = t & 63;
  const int wr = wid >> 1, wc = wid & 1;

  const int nwg = gridDim.x * gridDim.y;
  const int lbid = blockIdx.y * gridDim.x + blockIdx.x;
  const int q = nwg >> 3, r = nwg & 7;
  const int xcd = lbid & 7, li = lbid >> 3;
  const int wgid = (xcd < r ? xcd * (q + 1) : r * (q + 1) + (xcd - r) * q) + li;
  const int m0 = (wgid / gridDim.x) * TBM;
  const int n0 = (wgid % gridDim.x) * TBN;

  int srowA[2], srowB[2], gsl[2];
#pragma unroll
  for (int i = 0; i < 2; i++) {
    int row = i * 64 + (t >> 2);
    int ar = m0 + row;
    srowA[i] = (ar < M) ? ar : (M - 1);
    srowB[i] = n0 + row;
    gsl[i] = ((t & 3) ^ ((row >> 1) & 3)) * 8;
  }

  f32x4 acc[4][4] = {};
  const int nt = K / TBK;
  int cur = 0;

#pragma unroll
  for (int i = 0; i < 2; i++) {
    const int ldsoff = (i * 256 + wid * 64) * 8;
    __builtin_amdgcn_global_load_lds(
        (const __attribute__((address_space(1))) void*)(A + (size_t)srowA[i] * K + gsl[i]),
        (__attribute__((address_space(3))) void*)(lds[0] + ldsoff), 16, 0, 0);
    __builtin_amdgcn_global_load_lds(
        (const __attribute__((address_space(1))) void*)(Bt + (size_t)srowB[i] * K + gsl[i]),
        (__attribute__((address_space(3))) void*)(lds[1] + ldsoff), 16, 0, 0);
  }
  __syncthreads();

  const int rl = lane & 15, kh = lane >> 4;
  for (int tk = 0; tk < nt; ++tk) {
    if (tk + 1 < nt) {
      const int k0 = (tk + 1) * TBK;
      const int nb = (cur ^ 1) * 2;
#pragma unroll
      for (int i = 0; i < 2; i++) {
        const int ldsoff = (i * 256 + wid * 64) * 8;
        __builtin_amdgcn_global_load_lds(
            (const __attribute__((address_space(1))) void*)(A + (size_t)srowA[i] * K + k0 + gsl[i]),
            (__attribute__((address_space(3))) void*)(lds[nb] + ldsoff), 16, 0, 0);
        __builtin_amdgcn_global_load_lds(
            (const __attribute__((address_space(1))) void*)(Bt + (size_t)srowB[i] * K + k0 + gsl[i]),
            (__attribute__((address_space(3))) void*)(lds[nb + 1] + ldsoff), 16, 0, 0);
      }
    }
    {
      const ushort* As = lds[cur * 2];
      const ushort* Bs = lds[cur * 2 + 1];
      bf16x8 afr[4], bfr[4];
#pragma unroll
      for (int ni = 0; ni < 4; ni++) {
        int rowb = wc * 64 + ni * 16 + rl;
        int p = kh ^ ((rowb >> 1) & 3);
        bfr[ni] = *reinterpret_cast<const bf16x8*>(Bs + rowb * 32 + p * 8);
      }
#pragma unroll
      for (int mi = 0; mi < 4; mi++) {
        int rowa = wr * 64 + mi * 16 + rl;
        int p = kh ^ ((rowa >> 1) & 3);
        afr[mi] = *reinterpret_cast<const bf16x8*>(As + rowa * 32 + p * 8);
      }
#pragma unroll
      for (int mi = 0; mi < 4; mi++)
#pragma unroll
        for (int ni = 0; ni < 4; ni++)
          acc[mi][ni] = __builtin_amdgcn_mfma_f32_16x16x32_bf16(afr[mi], bfr[ni], acc[mi][ni], 0, 0, 0);
    }
    __syncthreads();
    cur ^= 1;
  }

  ushort* ldsC = lds[0];
  const int rgrp = lane >> 4, cl = lane & 15;
#pragma unroll
  for (int pass = 0; pass < 2; ++pass) {
    if (wr == pass) {
#pragma unroll
      for (int mi = 0; mi < 4; mi++) {
#pragma unroll
        for (int ni = 0; ni < 4; ni++) {
          int col = wc * 64 + ni * 16 + cl;
          float bv = bias[n0 + col];
#pragma unroll
          for (int r = 0; r < 4; r++) {
            int rloc = mi * 16 + rgrp * 4 + r;
            float v = acc[mi][ni][r] + bv;
            if (RELU) v = fmaxf(v, 0.f);
            ldsC[rloc * 132 + col] = f32_to_bf16(v);
          }
        }
      }
    }
    __syncthreads();
    {
      int rloc = t >> 2;
      int row = m0 + pass * 64 + rloc;
      if (row < M) {
#pragma unroll
        for (int j = 0; j < 4; j++) {
          int col = (t & 3) * 32 + j * 8;
          uint4 v = *reinterpret_cast<const uint4*>(ldsC + rloc * 132 + col);
          if (SPLIT) {
            int gcol = n0 + col;
            if (gcol < 256)
              *reinterpret_cast<uint4*>(C + (size_t)row * 256 + gcol) = v;
            else if (gcol < 448)
              *reinterpret_cast<uint4*>(C2 + (size_t)row * 192 + (gcol - 256)) = v;
          } else if (!NMASK || n0 + col < Nreal) {
            *reinterpret_cast<uint4*>(C + (size_t)row * ldc + n0 + col) = v;
          }
        }
      }
    }
    __syncthreads();
  }
}

// ---------------- fused out-proj + bias + residual + LN0 -------------------
__global__ __launch_bounds__(256, 2) void outproj_ln0_kernel(
    const ushort* __restrict__ samp,  // frag-order, 16384 us per 64-row block
    const ushort* __restrict__ wqf,   // 8 stages x 8192 us
    const float* __restrict__ bias,   // [256]
    const float* __restrict__ query,  // [M][256] f32
    const float* __restrict__ g0, const float* __restrict__ be0,
    ushort* __restrict__ xb,          // ffn frag-order, 32768 us per 128-row blk
    int M) {
  __shared__ ushort lds_all[32768];          // 64 KB
  ushort* As = lds_all;                      // 16384 us, frag-order
  ushort* ring0 = lds_all + 16384;           // 2 x 8192 us

  const int t = threadIdx.x;
  const int wv = t >> 6;
  const int lane = t & 63;
  const int rl = lane & 15, kq = lane >> 4;
  const int cl = lane & 15, g4 = lane >> 4;
  const int m0 = blockIdx.x * 64;

  ushort* ring[2] = {ring0, ring0 + 8192};

  auto issueB = [&](int j, ushort* dst) {
#pragma unroll
    for (int ii = 0; ii < 4; ++ii) {
      int c = t + 256 * ii;
      __builtin_amdgcn_global_load_lds(
          (const __attribute__((address_space(1))) void*)(wqf + (size_t)j * 8192 + (size_t)c * 8),
          (__attribute__((address_space(3))) void*)(dst + (size_t)c * 8), 16, 0, 0);
    }
  };

#pragma unroll
  for (int ii = 0; ii < 8; ++ii) {
    int c = t + 256 * ii;
    __builtin_amdgcn_global_load_lds(
        (const __attribute__((address_space(1))) void*)(
            samp + (size_t)blockIdx.x * 16384 + (size_t)c * 8),
        (__attribute__((address_space(3))) void*)(As + (size_t)c * 8), 16, 0, 0);
  }
  issueB(0, ring[0]);
  __syncthreads();

  f32x4 accF[4][4] = {};
  int cur = 0;

#pragma unroll
  for (int j = 0; j < 8; ++j) {
    if (j + 1 < 8) issueB(j + 1, ring[cur ^ 1]);
    const ushort* Bs = ring[cur];
    bf16x8 afr[4], bfr[4];
#pragma unroll
    for (int mi = 0; mi < 4; mi++)
      afr[mi] = *reinterpret_cast<const bf16x8*>(As + (j * 4 + kq) * 512 + (mi * 16 + rl) * 8);
#pragma unroll
    for (int ni = 0; ni < 4; ni++)
      bfr[ni] = *reinterpret_cast<const bf16x8*>(Bs + kq * 2048 + (wv * 64 + ni * 16 + rl) * 8);
    __builtin_amdgcn_s_setprio(1);
#pragma unroll
    for (int mi = 0; mi < 4; mi++)
#pragma unroll
      for (int ni = 0; ni < 4; ni++)
        accF[mi][ni] = __builtin_amdgcn_mfma_f32_16x16x32_bf16(afr[mi], bfr[ni], accF[mi][ni], 0, 0, 0);
    __builtin_amdgcn_s_setprio(0);
    __syncthreads();
    cur ^= 1;
  }

  float* ptab = (float*)ring0;
  float* mtab = (float*)(ring0 + 2048);

  float bc[4], gc[4], bec[4];
#pragma unroll
  for (int ni = 0; ni < 4; ni++) {
    int col = wv * 64 + ni * 16 + cl;
    bc[ni] = bias[col]; gc[ni] = g0[col]; bec[ni] = be0[col];
  }
#pragma unroll
  for (int mi = 0; mi < 4; mi++) {
#pragma unroll
    for (int ni = 0; ni < 4; ni++) {
      int col = wv * 64 + ni * 16 + cl;
#pragma unroll
      for (int r = 0; r < 4; r++) {
        int row = mi * 16 + g4 * 4 + r;
        int qrow = m0 + row; qrow = (qrow < M) ? qrow : (M - 1);
        accF[mi][ni][r] += bc[ni] + query[(size_t)qrow * 256 + col];
      }
    }
  }
#pragma unroll
  for (int mi = 0; mi < 4; mi++) {
#pragma unroll
    for (int r = 0; r < 4; r++) {
      float s = accF[mi][0][r] + accF[mi][1][r] + accF[mi][2][r] + accF[mi][3][r];
      float sq = accF[mi][0][r] * accF[mi][0][r] + accF[mi][1][r] * accF[mi][1][r] +
                 accF[mi][2][r] * accF[mi][2][r] + accF[mi][3][r] * accF[mi][3][r];
#pragma unroll
      for (int o = 1; o < 16; o <<= 1) {
        s += __shfl_xor(s, o, 64);
        sq += __shfl_xor(sq, o, 64);
      }
      if (cl == 0) {
        int row = mi * 16 + g4 * 4 + r;
        ptab[(row * 4 + wv) * 2 + 0] = s;
        ptab[(row * 4 + wv) * 2 + 1] = sq;
      }
    }
  }
  __syncthreads();
  {
    int row = t >> 2, part = t & 3;
    float s = ptab[(row * 4 + part) * 2 + 0];
    float sq = ptab[(row * 4 + part) * 2 + 1];
    s += __shfl_xor(s, 1, 64);  sq += __shfl_xor(sq, 1, 64);
    s += __shfl_xor(s, 2, 64);  sq += __shfl_xor(sq, 2, 64);
    if (part == 0) {
      float mean = s * (1.f / 256.f);
      float var = sq * (1.f / 256.f) - mean * mean;
      mtab[row * 2 + 0] = mean;
      mtab[row * 2 + 1] = rsqrtf(var + 1e-5f);
    }
  }
  __syncthreads();
  // LN -> As in frag-order (LDS), then coalesced linear copy to xb
#pragma unroll
  for (int mi = 0; mi < 4; mi++) {
#pragma unroll
    for (int r = 0; r < 4; r++) {
      int row = mi * 16 + g4 * 4 + r;
      float2 ms = *reinterpret_cast<const float2*>(mtab + row * 2);
#pragma unroll
      for (int ni = 0; ni < 4; ni++) {
        int col = wv * 64 + ni * 16 + cl;
        As[(col >> 3) * 512 + row * 8 + (col & 7)] =
            f32_to_bf16((accF[mi][ni][r] - ms.x) * ms.y * gc[ni] + bec[ni]);
      }
    }
  }
  __syncthreads();
  {
    const size_t base128 = (size_t)(blockIdx.x >> 1) * 32768 + (size_t)(blockIdx.x & 1) * 512;
#pragma unroll
    for (int ii = 0; ii < 8; ++ii) {
      int c = t + 256 * ii;
      int s = c >> 6, rl2 = c & 63;
      if (m0 + rl2 < M)
        *reinterpret_cast<uint4*>(xb + base128 + (size_t)s * 1024 + (size_t)rl2 * 8) =
            *reinterpret_cast<const uint4*>(As + (size_t)c * 8);
    }
  }
}

// ---------------- fused FFN1+ReLU+FFN2+residual+LN1 ------------------------
__global__ __launch_bounds__(512, 1) void ffn_ln_fused_kernel(
    const ushort* __restrict__ xb, const ushort* __restrict__ w1f,
    const float* __restrict__ b1, const ushort* __restrict__ w2f,
    const float* __restrict__ b2, const float* __restrict__ g1,
    const float* __restrict__ be1, float* __restrict__ out, int M) {
  __shared__ ushort lds_all[73856];            // 147.7 KB
  ushort* As = lds_all;                        // 32768 us
  ushort* Hs = lds_all + 32768;                // 16512 us (16 planes x 1032)
  ushort* stg0 = lds_all + 49280;              // 3 x 8192 us

  const int t = threadIdx.x;
  const int wv = t >> 6;
  const int wm = wv >> 2;
  const int wn = wv & 3;
  const int lane = t & 63;
  const int rl = lane & 15, kq = lane >> 4;
  const int cl = lane & 15, g4 = lane >> 4;
  const int m0 = blockIdx.x * 128;

  auto stg = [&](int i) { return stg0 + i * 8192; };

  auto issueB1 = [&](int p, int j, ushort* dst) {
    const ushort* src = w1f + (size_t)(p * 4 + j) * 8192;
#pragma unroll
    for (int ii = 0; ii < 2; ++ii) {
      int c = t + 512 * ii;
      __builtin_amdgcn_global_load_lds(
          (const __attribute__((address_space(1))) void*)(src + (size_t)c * 8),
          (__attribute__((address_space(3))) void*)(dst + (size_t)c * 8), 16, 0, 0);
    }
  };
  auto issueB2 = [&](int p, int tt, ushort* dst) {
    const ushort* src = w2f + (size_t)(p * 4 + tt) * 8192;
#pragma unroll
    for (int ii = 0; ii < 2; ++ii) {
      int c = t + 512 * ii;
      __builtin_amdgcn_global_load_lds(
          (const __attribute__((address_space(1))) void*)(src + (size_t)c * 8),
          (__attribute__((address_space(3))) void*)(dst + (size_t)c * 8), 16, 0, 0);
    }
  };

#pragma unroll
  for (int ii = 0; ii < 8; ++ii) {
    int c = t + 512 * ii;
    __builtin_amdgcn_global_load_lds(
        (const __attribute__((address_space(1))) void*)(
            xb + (size_t)blockIdx.x * 32768 + (size_t)c * 8),
        (__attribute__((address_space(3))) void*)(As + (size_t)c * 8), 16, 0, 0);
  }
  issueB1(0, 0, stg(0));
  issueB1(0, 1, stg(1));
  asm volatile("s_waitcnt vmcnt(2)" ::: "memory");
  __builtin_amdgcn_s_barrier();

  f32x4 acc1[4][2] = {};
  f32x4 accF[4][4] = {};
  int cur = 0;

  for (int p = 0; p < 16; ++p) {
#pragma unroll
    for (int j = 0; j < 8; ++j) {
      int tgt = cur + 2; if (tgt >= 3) tgt -= 3;
      if (j <= 5) {
        const int j2 = j + 2;
        const int p2 = p + (j2 >> 3);
        if ((j2 & 7) < 4) issueB1(p2, j2 & 3, stg(tgt));
        else issueB2(p2, (j2 & 7) - 4, stg(tgt));
        asm volatile("s_waitcnt vmcnt(4) lgkmcnt(0)" ::: "memory");
      } else if (p < 15) {
        const int j2m = (j + 2) & 7;
        issueB1(p + 1, j2m, stg(tgt));
        asm volatile("s_waitcnt vmcnt(4) lgkmcnt(0)" ::: "memory");
      } else if (j == 6) {
        asm volatile("s_waitcnt vmcnt(2) lgkmcnt(0)" ::: "memory");
      } else {
        asm volatile("s_waitcnt vmcnt(0) lgkmcnt(0)" ::: "memory");
      }
      __builtin_amdgcn_s_barrier();
      __builtin_amdgcn_sched_barrier(0);

      const ushort* Bs = stg(cur);
      if (j < 4) {
        __builtin_amdgcn_s_setprio(1);
#pragma unroll
        for (int kk = 0; kk < 2; ++kk) {
          bf16x8 afr[4], bfr[2];
          const int slotA = j * 8 + kk * 4 + kq;
#pragma unroll
          for (int mi = 0; mi < 4; mi++)
            afr[mi] = *reinterpret_cast<const bf16x8*>(
                As + slotA * 1024 + (wm * 64 + mi * 16 + rl) * 8);
          const int slotB = kk * 4 + kq;
#pragma unroll
          for (int ni = 0; ni < 2; ni++)
            bfr[ni] = *reinterpret_cast<const bf16x8*>(
                Bs + slotB * 1024 + (wn * 32 + ni * 16 + rl) * 8);
#pragma unroll
          for (int mi = 0; mi < 4; mi++)
#pragma unroll
            for (int ni = 0; ni < 2; ni++)
              acc1[mi][ni] = __builtin_amdgcn_mfma_f32_16x16x32_bf16(afr[mi], bfr[ni], acc1[mi][ni], 0, 0, 0);
        }
        __builtin_amdgcn_s_setprio(0);
        if (j == 3) {
#pragma unroll
          for (int ni = 0; ni < 2; ni++) {
            int col = wn * 32 + ni * 16 + cl;
            float b1v = b1[p * 128 + col];
            const int s = col >> 3, w8 = col & 7;
#pragma unroll
            for (int mi = 0; mi < 4; mi++) {
#pragma unroll
              for (int r = 0; r < 4; r++) {
                int row = wm * 64 + mi * 16 + g4 * 4 + r;
                Hs[s * 1032 + row * 8 + w8] = f32_to_bf16(fmaxf(acc1[mi][ni][r] + b1v, 0.f));
              }
            }
          }
#pragma unroll
          for (int mi = 0; mi < 4; mi++)
#pragma unroll
            for (int ni = 0; ni < 2; ni++)
              acc1[mi][ni] = (f32x4){0.f, 0.f, 0.f, 0.f};
        }
      } else {
        const int tt = j - 4;
        bf16x8 a2f[4], b2f[4];
#pragma unroll
        for (int mi = 0; mi < 4; mi++)
          a2f[mi] = *reinterpret_cast<const bf16x8*>(
              Hs + (tt * 4 + kq) * 1032 + (wm * 64 + mi * 16 + rl) * 8);
#pragma unroll
        for (int ni = 0; ni < 4; ni++)
          b2f[ni] = *reinterpret_cast<const bf16x8*>(
              Bs + kq * 2048 + (wn * 64 + ni * 16 + rl) * 8);
        __builtin_amdgcn_s_setprio(1);
#pragma unroll
        for (int mi = 0; mi < 4; mi++)
#pragma unroll
          for (int ni = 0; ni < 4; ni++)
            accF[mi][ni] = __builtin_amdgcn_mfma_f32_16x16x32_bf16(a2f[mi], b2f[ni], accF[mi][ni], 0, 0, 0);
        __builtin_amdgcn_s_setprio(0);
      }
      cur = cur + 1; if (cur >= 3) cur -= 3;
    }
  }

  float* ptab = (float*)stg0;
  float* mtab = (float*)(stg0 + 2048);

  float b2c[4], g1c[4], bec[4];
#pragma unroll
  for (int ni = 0; ni < 4; ni++) {
    int col = wn * 64 + ni * 16 + cl;
    b2c[ni] = b2[col]; g1c[ni] = g1[col]; bec[ni] = be1[col];
  }
#pragma unroll
  for (int mi = 0; mi < 4; mi++) {
#pragma unroll
    for (int ni = 0; ni < 4; ni++) {
      int col = wn * 64 + ni * 16 + cl;
#pragma unroll
      for (int r = 0; r < 4; r++) {
        int row = wm * 64 + mi * 16 + g4 * 4 + r;
        ushort xv = As[(col >> 3) * 1024 + row * 8 + (col & 7)];
        accF[mi][ni][r] += b2c[ni] + bf16_to_f32(xv);
      }
    }
  }
#pragma unroll
  for (int mi = 0; mi < 4; mi++) {
#pragma unroll
    for (int r = 0; r < 4; r++) {
      float s = accF[mi][0][r] + accF[mi][1][r] + accF[mi][2][r] + accF[mi][3][r];
      float sq = accF[mi][0][r] * accF[mi][0][r] + accF[mi][1][r] * accF[mi][1][r] +
                 accF[mi][2][r] * accF[mi][2][r] + accF[mi][3][r] * accF[mi][3][r];
#pragma unroll
      for (int o = 1; o < 16; o <<= 1) {
        s += __shfl_xor(s, o, 64);
        sq += __shfl_xor(sq, o, 64);
      }
      if (cl == 0) {
        int row = wm * 64 + mi * 16 + g4 * 4 + r;
        ptab[(row * 4 + wn) * 2 + 0] = s;
        ptab[(row * 4 + wn) * 2 + 1] = sq;
      }
    }
  }
  __syncthreads();
  {
    int row = t >> 2, part = t & 3;
    float s = ptab[(row * 4 + part) * 2 + 0];
    float sq = ptab[(row * 4 + part) * 2 + 1];
    s += __shfl_xor(s, 1, 64);  sq += __shfl_xor(sq, 1, 64);
    s += __shfl_xor(s, 2, 64);  sq += __shfl_xor(sq, 2, 64);
    if (part == 0) {
      float mean = s * (1.f / 256.f);
      float var = sq * (1.f / 256.f) - mean * mean;
      mtab[row * 2 + 0] = mean;
      mtab[row * 2 + 1] = rsqrtf(var + 1e-5f);
    }
  }
  __syncthreads();
#pragma unroll
  for (int mi = 0; mi < 4; mi++) {
#pragma unroll
    for (int r = 0; r < 4; r++) {
      int row = wm * 64 + mi * 16 + g4 * 4 + r;
      float2 ms = *reinterpret_cast<const float2*>(mtab + row * 2);
      int grow = m0 + row;
      if (grow < M) {
#pragma unroll
        for (int ni = 0; ni < 4; ni++) {
          int col = wn * 64 + ni * 16 + cl;
          out[(size_t)grow * 256 + col] = (accF[mi][ni][r] - ms.x) * ms.y * g1c[ni] + bec[ni];
        }
      }
    }
  }
}

// ---------------- deformable attention sampling ----------------------------
// R12 access pattern (4 lanes per (row,h): 64B-coalesced gathers, lane-coop
// softmax) + 4KB LDS repack so the frag-order store is in 128B runs.
// Block covers 8 rows x 8 heads x 4 chan-groups.
__global__ __launch_bounds__(256) void deform_attn_kernel(
    const ushort* __restrict__ val,  // [R][256] bf16
    const ushort* __restrict__ oa,   // [R][192] bf16: off 0..127 | aw 128..191
    const float* __restrict__ refp,  // [R][4]
    ushort* __restrict__ out,        // frag-order, 16384 us per 64-row block
    int R) {
  __shared__ ushort repack[2048];    // [s 0..31][rloc 0..7][8]

  const int t = threadIdx.x;
  const int c = t & 3;
  const int h = (t >> 2) & 7;
  const int rloc = t >> 5;
  const int row0 = blockIdx.x * 8;
  const int row = row0 + rloc;

  if (row < R) {
    const int bl = row / NQv;
    const ushort* orow = oa + (size_t)row * 192;

    // softmax partials: lane c holds logits 2c, 2c+1 (4-lane group)
    uint lraw = *reinterpret_cast<const uint*>(orow + 128 + h * 8 + c * 2);
    float l0 = bf16_to_f32((ushort)(lraw & 0xffffu));
    float l1 = bf16_to_f32((ushort)(lraw >> 16));
    float mx = fmaxf(l0, l1);
    mx = fmaxf(mx, __shfl_xor(mx, 1, 64));
    mx = fmaxf(mx, __shfl_xor(mx, 2, 64));
    float e0 = __expf(l0 - mx), e1 = __expf(l1 - mx);
    float sm = e0 + e1;
    sm += __shfl_xor(sm, 1, 64);
    sm += __shfl_xor(sm, 2, 64);
    float inv = 1.f / sm;

    ushort o4[4];
    *reinterpret_cast<uint2*>(o4) = *reinterpret_cast<const uint2*>(orow + h * 16 + c * 4);
    float4 rp = *reinterpret_cast<const float4*>(refp + (size_t)row * 4);
    float Wl = (c & 2) ? 50.f : 100.f;
    float fx = ((c & 2) ? rp.z : rp.x) * Wl - 0.5f;
    float fy = ((c & 2) ? rp.w : rp.y) * Wl - 0.5f;
    float myx0 = fx + bf16_to_f32(o4[0]);
    float myy0 = fy + bf16_to_f32(o4[1]);
    float myx1 = fx + bf16_to_f32(o4[2]);
    float myy1 = fy + bf16_to_f32(o4[3]);
    float myw0 = e0 * inv, myw1 = e1 * inv;

    const int lanebase = (t & 63) & ~3;
    float acc8[8] = {};
#pragma unroll
    for (int p = 0; p < 8; ++p) {
      const int src = lanebase | (p >> 1);
      float x = __shfl((p & 1) ? myx1 : myx0, src, 64);
      float y = __shfl((p & 1) ? myy1 : myy0, src, 64);
      float w = __shfl((p & 1) ? myw1 : myw0, src, 64);
      const int W = (p < 4) ? 100 : 50, H = W;
      const ushort* vbase = val + ((size_t)bl * NQv + ((p < 4) ? 0 : 10000)) * 256 + h * 32 + c * 8;
      float x0f = floorf(x), y0f = floorf(y);
      float wx1 = x - x0f, wy1 = y - y0f;
      float wx0 = 1.f - wx1, wy0 = 1.f - wy1;
      int x0 = (int)x0f, y0 = (int)y0f;
      float cw[4] = {w * wx0 * wy0, w * wx1 * wy0, w * wx0 * wy1, w * wx1 * wy1};
      int cx[4] = {x0, x0 + 1, x0, x0 + 1};
      int cy[4] = {y0, y0, y0 + 1, y0 + 1};
#pragma unroll
      for (int cc = 0; cc < 4; cc++) {
        int xi = cx[cc], yi = cy[cc];
        if (xi >= 0 && xi < W && yi >= 0 && yi < H) {
          ushort vr[8];
          *reinterpret_cast<uint4*>(vr) =
              *reinterpret_cast<const uint4*>(vbase + (size_t)(yi * W + xi) * 256);
          float ww = cw[cc];
#pragma unroll
          for (int j = 0; j < 8; j++) acc8[j] += ww * bf16_to_f32(vr[j]);
        }
      }
    }

    ushort st[8];
#pragma unroll
    for (int j = 0; j < 8; j++) st[j] = f32_to_bf16(acc8[j]);
    // repack[s= h*4+c][rloc]
    *reinterpret_cast<uint4*>(repack + (size_t)(h * 4 + c) * 64 + (size_t)rloc * 8) =
        *reinterpret_cast<uint4*>(st);
  }
  __syncthreads();

  // coalesced frag-order store: thread t -> (s2 = t>>3, r2 = t&7)
  {
    int s2 = t >> 3, r2 = t & 7;
    int grow = row0 + r2;
    if (grow < R) {
      int b64 = row0 >> 6, inner = (row0 & 63) + r2;
      *reinterpret_cast<uint4*>(out + (size_t)b64 * 16384 + (size_t)s2 * 512 + (size_t)inner * 8) =
          *reinterpret_cast<const uint4*>(repack + (size_t)s2 * 64 + (size_t)r2 * 8);
    }
  }
}

// ---------------------------------------------------------------------------
extern "C" void kernel_launch(void* const* d_in, const int* in_sizes, int n_in,
                              void* d_out, int out_size, void* d_ws, size_t ws_size,
                              hipStream_t stream) {
  const float* query  = (const float*)d_in[0];
  const float* refp   = (const float*)d_in[1];
  const float* w_off  = (const float*)d_in[2];
  const float* b_off  = (const float*)d_in[3];
  const float* w_attn = (const float*)d_in[4];
  const float* b_attn = (const float*)d_in[5];
  const float* w_val  = (const float*)d_in[6];
  const float* b_val  = (const float*)d_in[7];
  const float* w_out  = (const float*)d_in[8];
  const float* b_out  = (const float*)d_in[9];
  const float* w1     = (const float*)d_in[10];
  const float* b1     = (const float*)d_in[11];
  const float* w2     = (const float*)d_in[12];
  const float* b2     = (const float*)d_in[13];
  const float* ln0g   = (const float*)d_in[14];
  const float* ln0b   = (const float*)d_in[15];
  const float* ln1g   = (const float*)d_in[16];
  const float* ln1b   = (const float*)d_in[17];
  float* outp = (float*)d_out;

  char* ws = (char*)d_ws;
  size_t woff = 0;
  auto walloc = [&](size_t bytes) { size_t r = woff; woff += (bytes + 255) & ~(size_t)255; return r; };
  ushort* wcat = (ushort*)(ws + walloc((size_t)512 * 256 * 2));
  float*  bcat = (float*)(ws + walloc(512 * 4));
  ushort* wqt  = (ushort*)(ws + walloc((size_t)256 * 256 * 2));
  ushort* w1t  = (ushort*)(ws + walloc((size_t)DFF * 256 * 2));
  ushort* w2t  = (ushort*)(ws + walloc((size_t)256 * DFF * 2));
  ushort* wqf  = (ushort*)(ws + walloc((size_t)8 * 8192 * 2));
  ushort* w1f  = (ushort*)(ws + walloc((size_t)64 * 8192 * 2));
  ushort* w2f  = (ushort*)(ws + walloc((size_t)64 * 8192 * 2));
  char* arena = ws + woff;
  size_t arena_sz = (ws_size > woff) ? (ws_size - woff) : 0;

  int nb = ((size_t)BSv * NQv * 1920 + (4u << 20) <= arena_sz) ? BSv : 1;
  const int R = nb * NQv;
  const size_t xbsz = (size_t)((R + 127) / 128) * 65536;   // frag-order xb bytes
  ushort* qb   = (ushort*)arena;                           // row-major, then xb
  ushort* valb = (ushort*)(arena + xbsz);
  ushort* oab  = (ushort*)(arena + xbsz + (size_t)R * 512);
  ushort* samp = (ushort*)(arena + xbsz + (size_t)R * 512 + (size_t)R * 384);
  ushort* xb   = qb;

  build_wcat_kernel<<<dim3(448), dim3(256), 0, stream>>>(
      w_val, w_off, w_attn, b_val, b_off, b_attn, wcat, bcat);
  ttrans_kernel<<<dim3(4, 4), dim3(256), 0, stream>>>(w_out, wqt, Dv, Dv);
  ttrans_kernel<<<dim3(DFF / 64, 4), dim3(256), 0, stream>>>(w1, w1t, Dv, DFF);
  ttrans_kernel<<<dim3(4, DFF / 64), dim3(256), 0, stream>>>(w2, w2t, DFF, Dv);
  stagefmt_kernel<2><<<dim3(32), dim3(256), 0, stream>>>(wqt, wqf);
  stagefmt_kernel<0><<<dim3(256), dim3(256), 0, stream>>>(w1t, w1f);
  stagefmt_kernel<1><<<dim3(256), dim3(256), 0, stream>>>(w2t, w2f);

  const int MT = (R + TBM - 1) / TBM;

  for (int c = 0; c < BSv / nb; c++) {
    const int row0 = c * R;
    const float* qrow = query + (size_t)row0 * Dv;

    conv_bf16_kernel<<<dim3((R * 64 + 255) / 256), dim3(256), 0, stream>>>(qrow, qb, R * 64);

    gemm128_kernel<0, 1, 1><<<dim3(4, MT), dim3(256), 0, stream>>>(
        qb, wcat, bcat, valb, oab, R, Dv, 448, 448);

    deform_attn_kernel<<<dim3((R + 7) / 8), dim3(256), 0, stream>>>(
        valb, oab, refp + (size_t)row0 * 4, samp, R);

    outproj_ln0_kernel<<<dim3((R + 63) / 64), dim3(256), 0, stream>>>(
        samp, wqf, b_out, qrow, ln0g, ln0b, xb, R);

    ffn_ln_fused_kernel<<<dim3((R + 127) / 128), dim3(512), 0, stream>>>(
        xb, w1f, b1, w2f, b2, ln1g, ln1b, outp + (size_t)row0 * 256, R);
  }
}

// Round 17
// 317.872 us; speedup vs baseline: 1.3084x; 1.0177x over previous
//
#include <hip/hip_runtime.h>

// ---------------------------------------------------------------------------
// SpecDetrTransformerEncoderLayer on MI355X (gfx950)
// BS=4 NQ=12500 D=256 HEADS=8 LEVELS=2 POINTS=4 HD=32 D_FF=2048
// ---------------------------------------------------------------------------

#define NQv 12500
#define BSv 4
#define Dv  256
#define DFF 2048

typedef __attribute__((ext_vector_type(8))) __bf16 bf16x8;
typedef __attribute__((ext_vector_type(4))) float f32x4;

__device__ __forceinline__ ushort f32_to_bf16(float f) {
  unsigned u = __float_as_uint(f);
  u += 0x7FFFu + ((u >> 16) & 1u);
  return (ushort)(u >> 16);
}
__device__ __forceinline__ float bf16_to_f32(ushort u) {
  return __uint_as_float(((unsigned)u) << 16);
}

// ---------------- elementwise f32 -> bf16 ----------------------------------
__global__ __launch_bounds__(256) void conv_bf16_kernel(
    const float* __restrict__ in, ushort* __restrict__ out, int n4) {
  int i = blockIdx.x * 256 + threadIdx.x;
  if (i >= n4) return;
  float4 v = reinterpret_cast<const float4*>(in)[i];
  uint2 st;
  st.x = (unsigned)f32_to_bf16(v.x) | ((unsigned)f32_to_bf16(v.y) << 16);
  st.y = (unsigned)f32_to_bf16(v.z) | ((unsigned)f32_to_bf16(v.w) << 16);
  reinterpret_cast<uint2*>(out)[i] = st;
}

// ------------- concat-transpose of the 3 projection weights ----------------
__global__ __launch_bounds__(256) void build_wcat_kernel(
    const float* __restrict__ w_val, const float* __restrict__ w_off,
    const float* __restrict__ w_attn, const float* __restrict__ b_val,
    const float* __restrict__ b_off, const float* __restrict__ b_attn,
    ushort* __restrict__ wcat, float* __restrict__ bcat) {
  int i = blockIdx.x * 256 + threadIdx.x;
  if (i < 448 * 256) {
    int n = i >> 8, k = i & 255;
    float v = (n < 256) ? w_val[(size_t)k * 256 + n]
              : (n < 384) ? w_off[(size_t)k * 128 + (n - 256)]
                          : w_attn[(size_t)k * 64 + (n - 384)];
    wcat[i] = f32_to_bf16(v);
  }
  if (i < 512)
    bcat[i] = (i < 256) ? b_val[i] : (i < 384) ? b_off[i - 256]
              : (i < 448) ? b_attn[i - 384] : 0.f;
}

// ------- fused transpose + stage-format: f32 src -> staged bf16 dst --------
// MODE 0: w1[256][2048] -> w1f (64 stages; stage g=(n>>7)*4+(k>>6);
//         in-stage us off = ((k>>3)&7)*1024 + (n&127)*8 + (k&7))
// MODE 1: w2[2048][256] -> w2f (64 stages; g=(k>>7)*4+((k>>5)&3);
//         off = ((k>>3)&3)*2048 + n*8 + (k&7))
// MODE 2: w_out[256][256] -> wqf (8 stages; g=k>>5;
//         off = ((k>>3)&3)*2048 + n*8 + (k&7))
// Each 64x64 tile: coalesced f32 reads, contiguous 1KB staged write runs.
template <int MODE>
__global__ __launch_bounds__(256) void ttrans_stage_kernel(
    const float* __restrict__ src, ushort* __restrict__ dst, int N) {
  __shared__ ushort tl[64][65];
  const int k0 = blockIdx.y * 64, n0 = blockIdx.x * 64;
  const int t = threadIdx.x;
#pragma unroll
  for (int i = 0; i < 16; ++i) {
    int idx = t + 256 * i;
    int kk = idx >> 6, nn = idx & 63;
    tl[kk][nn] = f32_to_bf16(src[(size_t)(k0 + kk) * N + n0 + nn]);
  }
  __syncthreads();
#pragma unroll
  for (int i = 0; i < 16; ++i) {
    int idx = t + 256 * i;             // [0, 4096)
    int off = idx & 511;               // nn*8 + kl
    int nn = off >> 3, kl = off & 7;
    if (MODE == 0) {
      int s = idx >> 9;                // 0..7
      int kk = s * 8 + kl;
      int g = (n0 >> 7) * 4 + (k0 >> 6);
      dst[(size_t)g * 8192 + s * 1024 + (n0 & 64) * 8 + off] = tl[kk][nn];
    } else {
      int gl = idx >> 11;              // 0..1
      int s = (idx >> 9) & 3;
      int kk = gl * 32 + s * 8 + kl;
      int g = (MODE == 1) ? ((k0 >> 7) * 4 + ((k0 & 64) >> 5) + gl)
                          : ((k0 >> 5) + gl);
      dst[(size_t)g * 8192 + s * 2048 + (size_t)(n0 + nn) * 8 + kl] = tl[kk][nn];
    }
  }
}

// ---------------- 2-phase double-buffered bf16 MFMA GEMM -------------------
#define TBM 128
#define TBN 128
#define TBK 32

template <int RELU, int NMASK, int SPLIT>
__global__ __launch_bounds__(256) void gemm128_kernel(
    const ushort* __restrict__ A, const ushort* __restrict__ Bt,
    const float* __restrict__ bias, ushort* __restrict__ C,
    ushort* __restrict__ C2,
    int M, int K, int ldc, int Nreal) {
  __shared__ ushort lds[4][TBM * TBK];

  const int t = threadIdx.x;
  const int wid = t >> 6, lane = t & 63;
  const int wr = wid >> 1, wc = wid & 1;

  const int nwg = gridDim.x * gridDim.y;
  const int lbid = blockIdx.y * gridDim.x + blockIdx.x;
  const int q = nwg >> 3, r = nwg & 7;
  const int xcd = lbid & 7, li = lbid >> 3;
  const int wgid = (xcd < r ? xcd * (q + 1) : r * (q + 1) + (xcd - r) * q) + li;
  const int m0 = (wgid / gridDim.x) * TBM;
  const int n0 = (wgid % gridDim.x) * TBN;

  int srowA[2], srowB[2], gsl[2];
#pragma unroll
  for (int i = 0; i < 2; i++) {
    int row = i * 64 + (t >> 2);
    int ar = m0 + row;
    srowA[i] = (ar < M) ? ar : (M - 1);
    srowB[i] = n0 + row;
    gsl[i] = ((t & 3) ^ ((row >> 1) & 3)) * 8;
  }

  f32x4 acc[4][4] = {};
  const int nt = K / TBK;
  int cur = 0;

#pragma unroll
  for (int i = 0; i < 2; i++) {
    const int ldsoff = (i * 256 + wid * 64) * 8;
    __builtin_amdgcn_global_load_lds(
        (const __attribute__((address_space(1))) void*)(A + (size_t)srowA[i] * K + gsl[i]),
        (__attribute__((address_space(3))) void*)(lds[0] + ldsoff), 16, 0, 0);
    __builtin_amdgcn_global_load_lds(
        (const __attribute__((address_space(1))) void*)(Bt + (size_t)srowB[i] * K + gsl[i]),
        (__attribute__((address_space(3))) void*)(lds[1] + ldsoff), 16, 0, 0);
  }
  __syncthreads();

  const int rl = lane & 15, kh = lane >> 4;
  for (int tk = 0; tk < nt; ++tk) {
    if (tk + 1 < nt) {
      const int k0 = (tk + 1) * TBK;
      const int nb = (cur ^ 1) * 2;
#pragma unroll
      for (int i = 0; i < 2; i++) {
        const int ldsoff = (i * 256 + wid * 64) * 8;
        __builtin_amdgcn_global_load_lds(
            (const __attribute__((address_space(1))) void*)(A + (size_t)srowA[i] * K + k0 + gsl[i]),
            (__attribute__((address_space(3))) void*)(lds[nb] + ldsoff), 16, 0, 0);
        __builtin_amdgcn_global_load_lds(
            (const __attribute__((address_space(1))) void*)(Bt + (size_t)srowB[i] * K + k0 + gsl[i]),
            (__attribute__((address_space(3))) void*)(lds[nb + 1] + ldsoff), 16, 0, 0);
      }
    }
    {
      const ushort* As = lds[cur * 2];
      const ushort* Bs = lds[cur * 2 + 1];
      bf16x8 afr[4], bfr[4];
#pragma unroll
      for (int ni = 0; ni < 4; ni++) {
        int rowb = wc * 64 + ni * 16 + rl;
        int p = kh ^ ((rowb >> 1) & 3);
        bfr[ni] = *reinterpret_cast<const bf16x8*>(Bs + rowb * 32 + p * 8);
      }
#pragma unroll
      for (int mi = 0; mi < 4; mi++) {
        int rowa = wr * 64 + mi * 16 + rl;
        int p = kh ^ ((rowa >> 1) & 3);
        afr[mi] = *reinterpret_cast<const bf16x8*>(As + rowa * 32 + p * 8);
      }
#pragma unroll
      for (int mi = 0; mi < 4; mi++)
#pragma unroll
        for (int ni = 0; ni < 4; ni++)
          acc[mi][ni] = __builtin_amdgcn_mfma_f32_16x16x32_bf16(afr[mi], bfr[ni], acc[mi][ni], 0, 0, 0);
    }
    __syncthreads();
    cur ^= 1;
  }

  ushort* ldsC = lds[0];
  const int rgrp = lane >> 4, cl = lane & 15;
#pragma unroll
  for (int pass = 0; pass < 2; ++pass) {
    if (wr == pass) {
#pragma unroll
      for (int mi = 0; mi < 4; mi++) {
#pragma unroll
        for (int ni = 0; ni < 4; ni++) {
          int col = wc * 64 + ni * 16 + cl;
          float bv = bias[n0 + col];
#pragma unroll
          for (int r = 0; r < 4; r++) {
            int rloc = mi * 16 + rgrp * 4 + r;
            float v = acc[mi][ni][r] + bv;
            if (RELU) v = fmaxf(v, 0.f);
            ldsC[rloc * 132 + col] = f32_to_bf16(v);
          }
        }
      }
    }
    __syncthreads();
    {
      int rloc = t >> 2;
      int row = m0 + pass * 64 + rloc;
      if (row < M) {
#pragma unroll
        for (int j = 0; j < 4; j++) {
          int col = (t & 3) * 32 + j * 8;
          uint4 v = *reinterpret_cast<const uint4*>(ldsC + rloc * 132 + col);
          if (SPLIT) {
            int gcol = n0 + col;
            if (gcol < 256)
              *reinterpret_cast<uint4*>(C + (size_t)row * 256 + gcol) = v;
            else if (gcol < 448)
              *reinterpret_cast<uint4*>(C2 + (size_t)row * 192 + (gcol - 256)) = v;
          } else if (!NMASK || n0 + col < Nreal) {
            *reinterpret_cast<uint4*>(C + (size_t)row * ldc + n0 + col) = v;
          }
        }
      }
    }
    __syncthreads();
  }
}

// ---------------- fused out-proj + bias + residual + LN0 -------------------
__global__ __launch_bounds__(256, 2) void outproj_ln0_kernel(
    const ushort* __restrict__ samp,  // frag-order, 16384 us per 64-row block
    const ushort* __restrict__ wqf,   // 8 stages x 8192 us
    const float* __restrict__ bias,   // [256]
    const float* __restrict__ query,  // [M][256] f32
    const float* __restrict__ g0, const float* __restrict__ be0,
    ushort* __restrict__ xb,          // ffn frag-order, 32768 us per 128-row blk
    int M) {
  __shared__ ushort lds_all[32768];          // 64 KB
  ushort* As = lds_all;                      // 16384 us, frag-order
  ushort* ring0 = lds_all + 16384;           // 2 x 8192 us

  const int t = threadIdx.x;
  const int wv = t >> 6;
  const int lane = t & 63;
  const int rl = lane & 15, kq = lane >> 4;
  const int cl = lane & 15, g4 = lane >> 4;
  const int m0 = blockIdx.x * 64;

  ushort* ring[2] = {ring0, ring0 + 8192};

  auto issueB = [&](int j, ushort* dst) {
#pragma unroll
    for (int ii = 0; ii < 4; ++ii) {
      int c = t + 256 * ii;
      __builtin_amdgcn_global_load_lds(
          (const __attribute__((address_space(1))) void*)(wqf + (size_t)j * 8192 + (size_t)c * 8),
          (__attribute__((address_space(3))) void*)(dst + (size_t)c * 8), 16, 0, 0);
    }
  };

#pragma unroll
  for (int ii = 0; ii < 8; ++ii) {
    int c = t + 256 * ii;
    __builtin_amdgcn_global_load_lds(
        (const __attribute__((address_space(1))) void*)(
            samp + (size_t)blockIdx.x * 16384 + (size_t)c * 8),
        (__attribute__((address_space(3))) void*)(As + (size_t)c * 8), 16, 0, 0);
  }
  issueB(0, ring[0]);
  __syncthreads();

  f32x4 accF[4][4] = {};
  int cur = 0;

#pragma unroll
  for (int j = 0; j < 8; ++j) {
    if (j + 1 < 8) issueB(j + 1, ring[cur ^ 1]);
    const ushort* Bs = ring[cur];
    bf16x8 afr[4], bfr[4];
#pragma unroll
    for (int mi = 0; mi < 4; mi++)
      afr[mi] = *reinterpret_cast<const bf16x8*>(As + (j * 4 + kq) * 512 + (mi * 16 + rl) * 8);
#pragma unroll
    for (int ni = 0; ni < 4; ni++)
      bfr[ni] = *reinterpret_cast<const bf16x8*>(Bs + kq * 2048 + (wv * 64 + ni * 16 + rl) * 8);
    __builtin_amdgcn_s_setprio(1);
#pragma unroll
    for (int mi = 0; mi < 4; mi++)
#pragma unroll
      for (int ni = 0; ni < 4; ni++)
        accF[mi][ni] = __builtin_amdgcn_mfma_f32_16x16x32_bf16(afr[mi], bfr[ni], accF[mi][ni], 0, 0, 0);
    __builtin_amdgcn_s_setprio(0);
    __syncthreads();
    cur ^= 1;
  }

  float* ptab = (float*)ring0;
  float* mtab = (float*)(ring0 + 2048);

  float bc[4], gc[4], bec[4];
#pragma unroll
  for (int ni = 0; ni < 4; ni++) {
    int col = wv * 64 + ni * 16 + cl;
    bc[ni] = bias[col]; gc[ni] = g0[col]; bec[ni] = be0[col];
  }
#pragma unroll
  for (int mi = 0; mi < 4; mi++) {
#pragma unroll
    for (int ni = 0; ni < 4; ni++) {
      int col = wv * 64 + ni * 16 + cl;
#pragma unroll
      for (int r = 0; r < 4; r++) {
        int row = mi * 16 + g4 * 4 + r;
        int qrow = m0 + row; qrow = (qrow < M) ? qrow : (M - 1);
        accF[mi][ni][r] += bc[ni] + query[(size_t)qrow * 256 + col];
      }
    }
  }
#pragma unroll
  for (int mi = 0; mi < 4; mi++) {
#pragma unroll
    for (int r = 0; r < 4; r++) {
      float s = accF[mi][0][r] + accF[mi][1][r] + accF[mi][2][r] + accF[mi][3][r];
      float sq = accF[mi][0][r] * accF[mi][0][r] + accF[mi][1][r] * accF[mi][1][r] +
                 accF[mi][2][r] * accF[mi][2][r] + accF[mi][3][r] * accF[mi][3][r];
#pragma unroll
      for (int o = 1; o < 16; o <<= 1) {
        s += __shfl_xor(s, o, 64);
        sq += __shfl_xor(sq, o, 64);
      }
      if (cl == 0) {
        int row = mi * 16 + g4 * 4 + r;
        ptab[(row * 4 + wv) * 2 + 0] = s;
        ptab[(row * 4 + wv) * 2 + 1] = sq;
      }
    }
  }
  __syncthreads();
  {
    int row = t >> 2, part = t & 3;
    float s = ptab[(row * 4 + part) * 2 + 0];
    float sq = ptab[(row * 4 + part) * 2 + 1];
    s += __shfl_xor(s, 1, 64);  sq += __shfl_xor(sq, 1, 64);
    s += __shfl_xor(s, 2, 64);  sq += __shfl_xor(sq, 2, 64);
    if (part == 0) {
      float mean = s * (1.f / 256.f);
      float var = sq * (1.f / 256.f) - mean * mean;
      mtab[row * 2 + 0] = mean;
      mtab[row * 2 + 1] = rsqrtf(var + 1e-5f);
    }
  }
  __syncthreads();
#pragma unroll
  for (int mi = 0; mi < 4; mi++) {
#pragma unroll
    for (int r = 0; r < 4; r++) {
      int row = mi * 16 + g4 * 4 + r;
      float2 ms = *reinterpret_cast<const float2*>(mtab + row * 2);
#pragma unroll
      for (int ni = 0; ni < 4; ni++) {
        int col = wv * 64 + ni * 16 + cl;
        As[(col >> 3) * 512 + row * 8 + (col & 7)] =
            f32_to_bf16((accF[mi][ni][r] - ms.x) * ms.y * gc[ni] + bec[ni]);
      }
    }
  }
  __syncthreads();
  {
    const size_t base128 = (size_t)(blockIdx.x >> 1) * 32768 + (size_t)(blockIdx.x & 1) * 512;
#pragma unroll
    for (int ii = 0; ii < 8; ++ii) {
      int c = t + 256 * ii;
      int s = c >> 6, rl2 = c & 63;
      if (m0 + rl2 < M)
        *reinterpret_cast<uint4*>(xb + base128 + (size_t)s * 1024 + (size_t)rl2 * 8) =
            *reinterpret_cast<const uint4*>(As + (size_t)c * 8);
    }
  }
}

// ---------------- fused FFN1+ReLU+FFN2+residual+LN1 ------------------------
__global__ __launch_bounds__(512, 1) void ffn_ln_fused_kernel(
    const ushort* __restrict__ xb, const ushort* __restrict__ w1f,
    const float* __restrict__ b1, const ushort* __restrict__ w2f,
    const float* __restrict__ b2, const float* __restrict__ g1,
    const float* __restrict__ be1, float* __restrict__ out, int M) {
  __shared__ ushort lds_all[73856];            // 147.7 KB
  ushort* As = lds_all;                        // 32768 us
  ushort* Hs = lds_all + 32768;                // 16512 us (16 planes x 1032)
  ushort* stg0 = lds_all + 49280;              // 3 x 8192 us

  const int t = threadIdx.x;
  const int wv = t >> 6;
  const int wm = wv >> 2;
  const int wn = wv & 3;
  const int lane = t & 63;
  const int rl = lane & 15, kq = lane >> 4;
  const int cl = lane & 15, g4 = lane >> 4;
  const int m0 = blockIdx.x * 128;

  auto stg = [&](int i) { return stg0 + i * 8192; };

  auto issueB1 = [&](int p, int j, ushort* dst) {
    const ushort* src = w1f + (size_t)(p * 4 + j) * 8192;
#pragma unroll
    for (int ii = 0; ii < 2; ++ii) {
      int c = t + 512 * ii;
      __builtin_amdgcn_global_load_lds(
          (const __attribute__((address_space(1))) void*)(src + (size_t)c * 8),
          (__attribute__((address_space(3))) void*)(dst + (size_t)c * 8), 16, 0, 0);
    }
  };
  auto issueB2 = [&](int p, int tt, ushort* dst) {
    const ushort* src = w2f + (size_t)(p * 4 + tt) * 8192;
#pragma unroll
    for (int ii = 0; ii < 2; ++ii) {
      int c = t + 512 * ii;
      __builtin_amdgcn_global_load_lds(
          (const __attribute__((address_space(1))) void*)(src + (size_t)c * 8),
          (__attribute__((address_space(3))) void*)(dst + (size_t)c * 8), 16, 0, 0);
    }
  };

#pragma unroll
  for (int ii = 0; ii < 8; ++ii) {
    int c = t + 512 * ii;
    __builtin_amdgcn_global_load_lds(
        (const __attribute__((address_space(1))) void*)(
            xb + (size_t)blockIdx.x * 32768 + (size_t)c * 8),
        (__attribute__((address_space(3))) void*)(As + (size_t)c * 8), 16, 0, 0);
  }
  issueB1(0, 0, stg(0));
  issueB1(0, 1, stg(1));
  asm volatile("s_waitcnt vmcnt(2)" ::: "memory");
  __builtin_amdgcn_s_barrier();

  f32x4 acc1[4][2] = {};
  f32x4 accF[4][4] = {};
  int cur = 0;

  for (int p = 0; p < 16; ++p) {
#pragma unroll
    for (int j = 0; j < 8; ++j) {
      int tgt = cur + 2; if (tgt >= 3) tgt -= 3;
      if (j <= 5) {
        const int j2 = j + 2;
        const int p2 = p + (j2 >> 3);
        if ((j2 & 7) < 4) issueB1(p2, j2 & 3, stg(tgt));
        else issueB2(p2, (j2 & 7) - 4, stg(tgt));
        asm volatile("s_waitcnt vmcnt(4) lgkmcnt(0)" ::: "memory");
      } else if (p < 15) {
        const int j2m = (j + 2) & 7;
        issueB1(p + 1, j2m, stg(tgt));
        asm volatile("s_waitcnt vmcnt(4) lgkmcnt(0)" ::: "memory");
      } else if (j == 6) {
        asm volatile("s_waitcnt vmcnt(2) lgkmcnt(0)" ::: "memory");
      } else {
        asm volatile("s_waitcnt vmcnt(0) lgkmcnt(0)" ::: "memory");
      }
      __builtin_amdgcn_s_barrier();
      __builtin_amdgcn_sched_barrier(0);

      const ushort* Bs = stg(cur);
      if (j < 4) {
        __builtin_amdgcn_s_setprio(1);
#pragma unroll
        for (int kk = 0; kk < 2; ++kk) {
          bf16x8 afr[4], bfr[2];
          const int slotA = j * 8 + kk * 4 + kq;
#pragma unroll
          for (int mi = 0; mi < 4; mi++)
            afr[mi] = *reinterpret_cast<const bf16x8*>(
                As + slotA * 1024 + (wm * 64 + mi * 16 + rl) * 8);
          const int slotB = kk * 4 + kq;
#pragma unroll
          for (int ni = 0; ni < 2; ni++)
            bfr[ni] = *reinterpret_cast<const bf16x8*>(
                Bs + slotB * 1024 + (wn * 32 + ni * 16 + rl) * 8);
#pragma unroll
          for (int mi = 0; mi < 4; mi++)
#pragma unroll
            for (int ni = 0; ni < 2; ni++)
              acc1[mi][ni] = __builtin_amdgcn_mfma_f32_16x16x32_bf16(afr[mi], bfr[ni], acc1[mi][ni], 0, 0, 0);
        }
        __builtin_amdgcn_s_setprio(0);
        if (j == 3) {
#pragma unroll
          for (int ni = 0; ni < 2; ni++) {
            int col = wn * 32 + ni * 16 + cl;
            float b1v = b1[p * 128 + col];
            const int s = col >> 3, w8 = col & 7;
#pragma unroll
            for (int mi = 0; mi < 4; mi++) {
#pragma unroll
              for (int r = 0; r < 4; r++) {
                int row = wm * 64 + mi * 16 + g4 * 4 + r;
                Hs[s * 1032 + row * 8 + w8] = f32_to_bf16(fmaxf(acc1[mi][ni][r] + b1v, 0.f));
              }
            }
          }
#pragma unroll
          for (int mi = 0; mi < 4; mi++)
#pragma unroll
            for (int ni = 0; ni < 2; ni++)
              acc1[mi][ni] = (f32x4){0.f, 0.f, 0.f, 0.f};
        }
      } else {
        const int tt = j - 4;
        bf16x8 a2f[4], b2f[4];
#pragma unroll
        for (int mi = 0; mi < 4; mi++)
          a2f[mi] = *reinterpret_cast<const bf16x8*>(
              Hs + (tt * 4 + kq) * 1032 + (wm * 64 + mi * 16 + rl) * 8);
#pragma unroll
        for (int ni = 0; ni < 4; ni++)
          b2f[ni] = *reinterpret_cast<const bf16x8*>(
              Bs + kq * 2048 + (wn * 64 + ni * 16 + rl) * 8);
        __builtin_amdgcn_s_setprio(1);
#pragma unroll
        for (int mi = 0; mi < 4; mi++)
#pragma unroll
          for (int ni = 0; ni < 4; ni++)
            accF[mi][ni] = __builtin_amdgcn_mfma_f32_16x16x32_bf16(a2f[mi], b2f[ni], accF[mi][ni], 0, 0, 0);
        __builtin_amdgcn_s_setprio(0);
      }
      cur = cur + 1; if (cur >= 3) cur -= 3;
    }
  }

  float* ptab = (float*)stg0;
  float* mtab = (float*)(stg0 + 2048);

  float b2c[4], g1c[4], bec[4];
#pragma unroll
  for (int ni = 0; ni < 4; ni++) {
    int col = wn * 64 + ni * 16 + cl;
    b2c[ni] = b2[col]; g1c[ni] = g1[col]; bec[ni] = be1[col];
  }
#pragma unroll
  for (int mi = 0; mi < 4; mi++) {
#pragma unroll
    for (int ni = 0; ni < 4; ni++) {
      int col = wn * 64 + ni * 16 + cl;
#pragma unroll
      for (int r = 0; r < 4; r++) {
        int row = wm * 64 + mi * 16 + g4 * 4 + r;
        ushort xv = As[(col >> 3) * 1024 + row * 8 + (col & 7)];
        accF[mi][ni][r] += b2c[ni] + bf16_to_f32(xv);
      }
    }
  }
#pragma unroll
  for (int mi = 0; mi < 4; mi++) {
#pragma unroll
    for (int r = 0; r < 4; r++) {
      float s = accF[mi][0][r] + accF[mi][1][r] + accF[mi][2][r] + accF[mi][3][r];
      float sq = accF[mi][0][r] * accF[mi][0][r] + accF[mi][1][r] * accF[mi][1][r] +
                 accF[mi][2][r] * accF[mi][2][r] + accF[mi][3][r] * accF[mi][3][r];
#pragma unroll
      for (int o = 1; o < 16; o <<= 1) {
        s += __shfl_xor(s, o, 64);
        sq += __shfl_xor(sq, o, 64);
      }
      if (cl == 0) {
        int row = wm * 64 + mi * 16 + g4 * 4 + r;
        ptab[(row * 4 + wn) * 2 + 0] = s;
        ptab[(row * 4 + wn) * 2 + 1] = sq;
      }
    }
  }
  __syncthreads();
  {
    int row = t >> 2, part = t & 3;
    float s = ptab[(row * 4 + part) * 2 + 0];
    float sq = ptab[(row * 4 + part) * 2 + 1];
    s += __shfl_xor(s, 1, 64);  sq += __shfl_xor(sq, 1, 64);
    s += __shfl_xor(s, 2, 64);  sq += __shfl_xor(sq, 2, 64);
    if (part == 0) {
      float mean = s * (1.f / 256.f);
      float var = sq * (1.f / 256.f) - mean * mean;
      mtab[row * 2 + 0] = mean;
      mtab[row * 2 + 1] = rsqrtf(var + 1e-5f);
    }
  }
  __syncthreads();
#pragma unroll
  for (int mi = 0; mi < 4; mi++) {
#pragma unroll
    for (int r = 0; r < 4; r++) {
      int row = wm * 64 + mi * 16 + g4 * 4 + r;
      float2 ms = *reinterpret_cast<const float2*>(mtab + row * 2);
      int grow = m0 + row;
      if (grow < M) {
#pragma unroll
        for (int ni = 0; ni < 4; ni++) {
          int col = wn * 64 + ni * 16 + cl;
          out[(size_t)grow * 256 + col] = (accF[mi][ni][r] - ms.x) * ms.y * g1c[ni] + bec[ni];
        }
      }
    }
  }
}

// ---------------- deformable attention sampling ----------------------------
__global__ __launch_bounds__(256) void deform_attn_kernel(
    const ushort* __restrict__ val,  // [R][256] bf16
    const ushort* __restrict__ oa,   // [R][192] bf16: off 0..127 | aw 128..191
    const float* __restrict__ refp,  // [R][4]
    ushort* __restrict__ out,        // frag-order, 16384 us per 64-row block
    int R) {
  __shared__ ushort repack[2048];    // [s 0..31][rloc 0..7][8]

  const int t = threadIdx.x;
  const int c = t & 3;
  const int h = (t >> 2) & 7;
  const int rloc = t >> 5;
  const int row0 = blockIdx.x * 8;
  const int row = row0 + rloc;

  if (row < R) {
    const int bl = row / NQv;
    const ushort* orow = oa + (size_t)row * 192;

    uint lraw = *reinterpret_cast<const uint*>(orow + 128 + h * 8 + c * 2);
    float l0 = bf16_to_f32((ushort)(lraw & 0xffffu));
    float l1 = bf16_to_f32((ushort)(lraw >> 16));
    float mx = fmaxf(l0, l1);
    mx = fmaxf(mx, __shfl_xor(mx, 1, 64));
    mx = fmaxf(mx, __shfl_xor(mx, 2, 64));
    float e0 = __expf(l0 - mx), e1 = __expf(l1 - mx);
    float sm = e0 + e1;
    sm += __shfl_xor(sm, 1, 64);
    sm += __shfl_xor(sm, 2, 64);
    float inv = 1.f / sm;

    ushort o4[4];
    *reinterpret_cast<uint2*>(o4) = *reinterpret_cast<const uint2*>(orow + h * 16 + c * 4);
    float4 rp = *reinterpret_cast<const float4*>(refp + (size_t)row * 4);
    float Wl = (c & 2) ? 50.f : 100.f;
    float fx = ((c & 2) ? rp.z : rp.x) * Wl - 0.5f;
    float fy = ((c & 2) ? rp.w : rp.y) * Wl - 0.5f;
    float myx0 = fx + bf16_to_f32(o4[0]);
    float myy0 = fy + bf16_to_f32(o4[1]);
    float myx1 = fx + bf16_to_f32(o4[2]);
    float myy1 = fy + bf16_to_f32(o4[3]);
    float myw0 = e0 * inv, myw1 = e1 * inv;

    const int lanebase = (t & 63) & ~3;
    float acc8[8] = {};
#pragma unroll
    for (int p = 0; p < 8; ++p) {
      const int src = lanebase | (p >> 1);
      float x = __shfl((p & 1) ? myx1 : myx0, src, 64);
      float y = __shfl((p & 1) ? myy1 : myy0, src, 64);
      float w = __shfl((p & 1) ? myw1 : myw0, src, 64);
      const int W = (p < 4) ? 100 : 50, H = W;
      const ushort* vbase = val + ((size_t)bl * NQv + ((p < 4) ? 0 : 10000)) * 256 + h * 32 + c * 8;
      float x0f = floorf(x), y0f = floorf(y);
      float wx1 = x - x0f, wy1 = y - y0f;
      float wx0 = 1.f - wx1, wy0 = 1.f - wy1;
      int x0 = (int)x0f, y0 = (int)y0f;
      float cw[4] = {w * wx0 * wy0, w * wx1 * wy0, w * wx0 * wy1, w * wx1 * wy1};
      int cx[4] = {x0, x0 + 1, x0, x0 + 1};
      int cy[4] = {y0, y0, y0 + 1, y0 + 1};
#pragma unroll
      for (int cc = 0; cc < 4; cc++) {
        int xi = cx[cc], yi = cy[cc];
        if (xi >= 0 && xi < W && yi >= 0 && yi < H) {
          ushort vr[8];
          *reinterpret_cast<uint4*>(vr) =
              *reinterpret_cast<const uint4*>(vbase + (size_t)(yi * W + xi) * 256);
          float ww = cw[cc];
#pragma unroll
          for (int j = 0; j < 8; j++) acc8[j] += ww * bf16_to_f32(vr[j]);
        }
      }
    }

    ushort st[8];
#pragma unroll
    for (int j = 0; j < 8; j++) st[j] = f32_to_bf16(acc8[j]);
    *reinterpret_cast<uint4*>(repack + (size_t)(h * 4 + c) * 64 + (size_t)rloc * 8) =
        *reinterpret_cast<uint4*>(st);
  }
  __syncthreads();

  {
    int s2 = t >> 3, r2 = t & 7;
    int grow = row0 + r2;
    if (grow < R) {
      int b64 = row0 >> 6, inner = (row0 & 63) + r2;
      *reinterpret_cast<uint4*>(out + (size_t)b64 * 16384 + (size_t)s2 * 512 + (size_t)inner * 8) =
          *reinterpret_cast<const uint4*>(repack + (size_t)s2 * 64 + (size_t)r2 * 8);
    }
  }
}

// ---------------------------------------------------------------------------
extern "C" void kernel_launch(void* const* d_in, const int* in_sizes, int n_in,
                              void* d_out, int out_size, void* d_ws, size_t ws_size,
                              hipStream_t stream) {
  const float* query  = (const float*)d_in[0];
  const float* refp   = (const float*)d_in[1];
  const float* w_off  = (const float*)d_in[2];
  const float* b_off  = (const float*)d_in[3];
  const float* w_attn = (const float*)d_in[4];
  const float* b_attn = (const float*)d_in[5];
  const float* w_val  = (const float*)d_in[6];
  const float* b_val  = (const float*)d_in[7];
  const float* w_out  = (const float*)d_in[8];
  const float* b_out  = (const float*)d_in[9];
  const float* w1     = (const float*)d_in[10];
  const float* b1     = (const float*)d_in[11];
  const float* w2     = (const float*)d_in[12];
  const float* b2     = (const float*)d_in[13];
  const float* ln0g   = (const float*)d_in[14];
  const float* ln0b   = (const float*)d_in[15];
  const float* ln1g   = (const float*)d_in[16];
  const float* ln1b   = (const float*)d_in[17];
  float* outp = (float*)d_out;

  char* ws = (char*)d_ws;
  size_t woff = 0;
  auto walloc = [&](size_t bytes) { size_t r = woff; woff += (bytes + 255) & ~(size_t)255; return r; };
  ushort* wcat = (ushort*)(ws + walloc((size_t)512 * 256 * 2));
  float*  bcat = (float*)(ws + walloc(512 * 4));
  ushort* wqf  = (ushort*)(ws + walloc((size_t)8 * 8192 * 2));
  ushort* w1f  = (ushort*)(ws + walloc((size_t)64 * 8192 * 2));
  ushort* w2f  = (ushort*)(ws + walloc((size_t)64 * 8192 * 2));
  char* arena = ws + woff;
  size_t arena_sz = (ws_size > woff) ? (ws_size - woff) : 0;

  int nb = ((size_t)BSv * NQv * 1920 + (4u << 20) <= arena_sz) ? BSv : 1;
  const int R = nb * NQv;
  const size_t xbsz = (size_t)((R + 127) / 128) * 65536;   // frag-order xb bytes
  ushort* qb   = (ushort*)arena;                           // row-major, then xb
  ushort* valb = (ushort*)(arena + xbsz);
  ushort* oab  = (ushort*)(arena + xbsz + (size_t)R * 512);
  ushort* samp = (ushort*)(arena + xbsz + (size_t)R * 512 + (size_t)R * 384);
  ushort* xb   = qb;

  build_wcat_kernel<<<dim3(448), dim3(256), 0, stream>>>(
      w_val, w_off, w_attn, b_val, b_off, b_attn, wcat, bcat);
  // fused transpose+stage: f32 weights -> staged bf16 images
  ttrans_stage_kernel<2><<<dim3(4, 4), dim3(256), 0, stream>>>(w_out, wqf, 256);
  ttrans_stage_kernel<0><<<dim3(32, 4), dim3(256), 0, stream>>>(w1, w1f, 2048);
  ttrans_stage_kernel<1><<<dim3(4, 32), dim3(256), 0, stream>>>(w2, w2f, 256);

  const int MT = (R + TBM - 1) / TBM;

  for (int c = 0; c < BSv / nb; c++) {
    const int row0 = c * R;
    const float* qrow = query + (size_t)row0 * Dv;

    conv_bf16_kernel<<<dim3((R * 64 + 255) / 256), dim3(256), 0, stream>>>(qrow, qb, R * 64);

    gemm128_kernel<0, 1, 1><<<dim3(4, MT), dim3(256), 0, stream>>>(
        qb, wcat, bcat, valb, oab, R, Dv, 448, 448);

    deform_attn_kernel<<<dim3((R + 7) / 8), dim3(256), 0, stream>>>(
        valb, oab, refp + (size_t)row0 * 4, samp, R);

    outproj_ln0_kernel<<<dim3((R + 63) / 64), dim3(256), 0, stream>>>(
        samp, wqf, b_out, qrow, ln0g, ln0b, xb, R);

    ffn_ln_fused_kernel<<<dim3((R + 127) / 128), dim3(512), 0, stream>>>(
        xb, w1f, b1, w2f, b2, ln1g, ln1b, outp + (size_t)row0 * 256, R);
  }
}

// Round 18
// 308.586 us; speedup vs baseline: 1.3478x; 1.0301x over previous
//
#include <hip/hip_runtime.h>

// ---------------------------------------------------------------------------
// SpecDetrTransformerEncoderLayer on MI355X (gfx950)
// BS=4 NQ=12500 D=256 HEADS=8 LEVELS=2 POINTS=4 HD=32 D_FF=2048
// ---------------------------------------------------------------------------

#define NQv 12500
#define BSv 4
#define Dv  256
#define DFF 2048

typedef __attribute__((ext_vector_type(8))) __bf16 bf16x8;
typedef __attribute__((ext_vector_type(4))) float f32x4;

__device__ __forceinline__ ushort f32_to_bf16(float f) {
  unsigned u = __float_as_uint(f);
  u += 0x7FFFu + ((u >> 16) & 1u);
  return (ushort)(u >> 16);
}
__device__ __forceinline__ float bf16_to_f32(ushort u) {
  return __uint_as_float(((unsigned)u) << 16);
}

// ---------------- elementwise f32 -> bf16 ----------------------------------
__global__ __launch_bounds__(256) void conv_bf16_kernel(
    const float* __restrict__ in, ushort* __restrict__ out, int n4) {
  int i = blockIdx.x * 256 + threadIdx.x;
  if (i >= n4) return;
  float4 v = reinterpret_cast<const float4*>(in)[i];
  uint2 st;
  st.x = (unsigned)f32_to_bf16(v.x) | ((unsigned)f32_to_bf16(v.y) << 16);
  st.y = (unsigned)f32_to_bf16(v.z) | ((unsigned)f32_to_bf16(v.w) << 16);
  reinterpret_cast<uint2*>(out)[i] = st;
}

// ------------- concat-transpose of the 3 projection weights ----------------
__global__ __launch_bounds__(256) void build_wcat_kernel(
    const float* __restrict__ w_val, const float* __restrict__ w_off,
    const float* __restrict__ w_attn, const float* __restrict__ b_val,
    const float* __restrict__ b_off, const float* __restrict__ b_attn,
    ushort* __restrict__ wcat, float* __restrict__ bcat) {
  int i = blockIdx.x * 256 + threadIdx.x;
  if (i < 448 * 256) {
    int n = i >> 8, k = i & 255;
    float v = (n < 256) ? w_val[(size_t)k * 256 + n]
              : (n < 384) ? w_off[(size_t)k * 128 + (n - 256)]
                          : w_attn[(size_t)k * 64 + (n - 384)];
    wcat[i] = f32_to_bf16(v);
  }
  if (i < 512)
    bcat[i] = (i < 256) ? b_val[i] : (i < 384) ? b_off[i - 256]
              : (i < 448) ? b_attn[i - 384] : 0.f;
}

// ------- fused transpose + stage-format: f32 src -> staged bf16 dst --------
template <int MODE>
__global__ __launch_bounds__(256) void ttrans_stage_kernel(
    const float* __restrict__ src, ushort* __restrict__ dst, int N) {
  __shared__ ushort tl[64][65];
  const int k0 = blockIdx.y * 64, n0 = blockIdx.x * 64;
  const int t = threadIdx.x;
#pragma unroll
  for (int i = 0; i < 16; ++i) {
    int idx = t + 256 * i;
    int kk = idx >> 6, nn = idx & 63;
    tl[kk][nn] = f32_to_bf16(src[(size_t)(k0 + kk) * N + n0 + nn]);
  }
  __syncthreads();
#pragma unroll
  for (int i = 0; i < 16; ++i) {
    int idx = t + 256 * i;             // [0, 4096)
    int off = idx & 511;               // nn*8 + kl
    int nn = off >> 3, kl = off & 7;
    if (MODE == 0) {
      int s = idx >> 9;                // 0..7
      int kk = s * 8 + kl;
      int g = (n0 >> 7) * 4 + (k0 >> 6);
      dst[(size_t)g * 8192 + s * 1024 + (n0 & 64) * 8 + off] = tl[kk][nn];
    } else {
      int gl = idx >> 11;              // 0..1
      int s = (idx >> 9) & 3;
      int kk = gl * 32 + s * 8 + kl;
      int g = (MODE == 1) ? ((k0 >> 7) * 4 + ((k0 & 64) >> 5) + gl)
                          : ((k0 >> 5) + gl);
      dst[(size_t)g * 8192 + s * 2048 + (size_t)(n0 + nn) * 8 + kl] = tl[kk][nn];
    }
  }
}

// ---------------- 2-phase double-buffered bf16 MFMA GEMM -------------------
#define TBM 128
#define TBN 128
#define TBK 32

template <int RELU, int NMASK, int SPLIT>
__global__ __launch_bounds__(256) void gemm128_kernel(
    const ushort* __restrict__ A, const ushort* __restrict__ Bt,
    const float* __restrict__ bias, ushort* __restrict__ C,
    ushort* __restrict__ C2,
    int M, int K, int ldc, int Nreal) {
  __shared__ ushort lds[4][TBM * TBK];

  const int t = threadIdx.x;
  const int wid = t >> 6, lane = t & 63;
  const int wr = wid >> 1, wc = wid & 1;

  const int nwg = gridDim.x * gridDim.y;
  const int lbid = blockIdx.y * gridDim.x + blockIdx.x;
  const int q = nwg >> 3, r = nwg & 7;
  const int xcd = lbid & 7, li = lbid >> 3;
  const int wgid = (xcd < r ? xcd * (q + 1) : r * (q + 1) + (xcd - r) * q) + li;
  const int m0 = (wgid / gridDim.x) * TBM;
  const int n0 = (wgid % gridDim.x) * TBN;

  int srowA[2], srowB[2], gsl[2];
#pragma unroll
  for (int i = 0; i < 2; i++) {
    int row = i * 64 + (t >> 2);
    int ar = m0 + row;
    srowA[i] = (ar < M) ? ar : (M - 1);
    srowB[i] = n0 + row;
    gsl[i] = ((t & 3) ^ ((row >> 1) & 3)) * 8;
  }

  f32x4 acc[4][4] = {};
  const int nt = K / TBK;
  int cur = 0;

#pragma unroll
  for (int i = 0; i < 2; i++) {
    const int ldsoff = (i * 256 + wid * 64) * 8;
    __builtin_amdgcn_global_load_lds(
        (const __attribute__((address_space(1))) void*)(A + (size_t)srowA[i] * K + gsl[i]),
        (__attribute__((address_space(3))) void*)(lds[0] + ldsoff), 16, 0, 0);
    __builtin_amdgcn_global_load_lds(
        (const __attribute__((address_space(1))) void*)(Bt + (size_t)srowB[i] * K + gsl[i]),
        (__attribute__((address_space(3))) void*)(lds[1] + ldsoff), 16, 0, 0);
  }
  __syncthreads();

  const int rl = lane & 15, kh = lane >> 4;
  for (int tk = 0; tk < nt; ++tk) {
    if (tk + 1 < nt) {
      const int k0 = (tk + 1) * TBK;
      const int nb = (cur ^ 1) * 2;
#pragma unroll
      for (int i = 0; i < 2; i++) {
        const int ldsoff = (i * 256 + wid * 64) * 8;
        __builtin_amdgcn_global_load_lds(
            (const __attribute__((address_space(1))) void*)(A + (size_t)srowA[i] * K + k0 + gsl[i]),
            (__attribute__((address_space(3))) void*)(lds[nb] + ldsoff), 16, 0, 0);
        __builtin_amdgcn_global_load_lds(
            (const __attribute__((address_space(1))) void*)(Bt + (size_t)srowB[i] * K + k0 + gsl[i]),
            (__attribute__((address_space(3))) void*)(lds[nb + 1] + ldsoff), 16, 0, 0);
      }
    }
    {
      const ushort* As = lds[cur * 2];
      const ushort* Bs = lds[cur * 2 + 1];
      bf16x8 afr[4], bfr[4];
#pragma unroll
      for (int ni = 0; ni < 4; ni++) {
        int rowb = wc * 64 + ni * 16 + rl;
        int p = kh ^ ((rowb >> 1) & 3);
        bfr[ni] = *reinterpret_cast<const bf16x8*>(Bs + rowb * 32 + p * 8);
      }
#pragma unroll
      for (int mi = 0; mi < 4; mi++) {
        int rowa = wr * 64 + mi * 16 + rl;
        int p = kh ^ ((rowa >> 1) & 3);
        afr[mi] = *reinterpret_cast<const bf16x8*>(As + rowa * 32 + p * 8);
      }
#pragma unroll
      for (int mi = 0; mi < 4; mi++)
#pragma unroll
        for (int ni = 0; ni < 4; ni++)
          acc[mi][ni] = __builtin_amdgcn_mfma_f32_16x16x32_bf16(afr[mi], bfr[ni], acc[mi][ni], 0, 0, 0);
    }
    __syncthreads();
    cur ^= 1;
  }

  ushort* ldsC = lds[0];
  const int rgrp = lane >> 4, cl = lane & 15;
#pragma unroll
  for (int pass = 0; pass < 2; ++pass) {
    if (wr == pass) {
#pragma unroll
      for (int mi = 0; mi < 4; mi++) {
#pragma unroll
        for (int ni = 0; ni < 4; ni++) {
          int col = wc * 64 + ni * 16 + cl;
          float bv = bias[n0 + col];
#pragma unroll
          for (int r = 0; r < 4; r++) {
            int rloc = mi * 16 + rgrp * 4 + r;
            float v = acc[mi][ni][r] + bv;
            if (RELU) v = fmaxf(v, 0.f);
            ldsC[rloc * 132 + col] = f32_to_bf16(v);
          }
        }
      }
    }
    __syncthreads();
    {
      int rloc = t >> 2;
      int row = m0 + pass * 64 + rloc;
      if (row < M) {
#pragma unroll
        for (int j = 0; j < 4; j++) {
          int col = (t & 3) * 32 + j * 8;
          uint4 v = *reinterpret_cast<const uint4*>(ldsC + rloc * 132 + col);
          if (SPLIT) {
            int gcol = n0 + col;
            if (gcol < 256)
              *reinterpret_cast<uint4*>(C + (size_t)row * 256 + gcol) = v;
            else if (gcol < 448)
              *reinterpret_cast<uint4*>(C2 + (size_t)row * 192 + (gcol - 256)) = v;
          } else if (!NMASK || n0 + col < Nreal) {
            *reinterpret_cast<uint4*>(C + (size_t)row * ldc + n0 + col) = v;
          }
        }
      }
    }
    __syncthreads();
  }
}

// ------- MEGA: out-proj + bias + residual + LN0 + FFN + LN1 ----------------
// 128 rows/block, 8 waves (2 M x 4 N). Phase 1 (out-proj): samp staged
// frag-order into As (64KB), wqf 2-ring in stg(0/1), 8 K-steps, LN0
// epilogue writes x DIRECTLY into As (ffn layout). Phase 2: R16 ffn loop
// unchanged (As already resident). ptab/mtab live in stg(2) during ph.1.
__global__ __launch_bounds__(512, 1) void attnout_ffn_kernel(
    const ushort* __restrict__ samp,  // frag-order, 16384 us per 64-row blk
    const ushort* __restrict__ wqf,   // 8 stages x 8192 us
    const float* __restrict__ b_out,
    const float* __restrict__ query,  // [M][256] f32
    const float* __restrict__ g0, const float* __restrict__ be0,
    const ushort* __restrict__ w1f,   // 64 stages x 8192 us
    const float* __restrict__ b1,
    const ushort* __restrict__ w2f,   // 64 stages x 8192 us
    const float* __restrict__ b2,
    const float* __restrict__ g1, const float* __restrict__ be1,
    float* __restrict__ out, int M) {
  __shared__ ushort lds_all[73856];            // 147.7 KB
  ushort* As = lds_all;                        // 32768 us
  ushort* Hs = lds_all + 32768;                // 16512 us (16 planes x 1032)
  ushort* stg0 = lds_all + 49280;              // 3 x 8192 us

  const int t = threadIdx.x;
  const int wv = t >> 6;
  const int wm = wv >> 2;
  const int wn = wv & 3;
  const int lane = t & 63;
  const int rl = lane & 15, kq = lane >> 4;
  const int cl = lane & 15, g4 = lane >> 4;
  const int m0 = blockIdx.x * 128;

  auto stg = [&](int i) { return stg0 + i * 8192; };

  f32x4 accF[4][4] = {};

  // ================= PHASE 1: out-proj + LN0 =================
  {
    auto issueWq = [&](int j, ushort* dst) {
#pragma unroll
      for (int ii = 0; ii < 2; ++ii) {
        int c = t + 512 * ii;
        __builtin_amdgcn_global_load_lds(
            (const __attribute__((address_space(1))) void*)(wqf + (size_t)j * 8192 + (size_t)c * 8),
            (__attribute__((address_space(3))) void*)(dst + (size_t)c * 8), 16, 0, 0);
      }
    };
    // stage samp (two 64-row frag blocks, linear) + wq stage 0
#pragma unroll
    for (int ii = 0; ii < 8; ++ii) {
      int c = t + 512 * ii;
      __builtin_amdgcn_global_load_lds(
          (const __attribute__((address_space(1))) void*)(
              samp + (size_t)blockIdx.x * 32768 + (size_t)c * 8),
          (__attribute__((address_space(3))) void*)(As + (size_t)c * 8), 16, 0, 0);
    }
    issueWq(0, stg(0));
    __syncthreads();

    int cur = 0;
#pragma unroll
    for (int j = 0; j < 8; ++j) {
      if (j + 1 < 8) issueWq(j + 1, stg(cur ^ 1));
      const ushort* Bs = stg(cur);
      bf16x8 afr[4], bfr[4];
#pragma unroll
      for (int mi = 0; mi < 4; mi++)
        afr[mi] = *reinterpret_cast<const bf16x8*>(
            As + wm * 16384 + (j * 4 + kq) * 512 + (mi * 16 + rl) * 8);
#pragma unroll
      for (int ni = 0; ni < 4; ni++)
        bfr[ni] = *reinterpret_cast<const bf16x8*>(
            Bs + kq * 2048 + (wn * 64 + ni * 16 + rl) * 8);
      __builtin_amdgcn_s_setprio(1);
#pragma unroll
      for (int mi = 0; mi < 4; mi++)
#pragma unroll
        for (int ni = 0; ni < 4; ni++)
          accF[mi][ni] = __builtin_amdgcn_mfma_f32_16x16x32_bf16(afr[mi], bfr[ni], accF[mi][ni], 0, 0, 0);
      __builtin_amdgcn_s_setprio(0);
      __syncthreads();
      cur ^= 1;
    }

    // LN0 epilogue: z = accF + b_out + query; LN; x -> As (ffn layout)
    float* ptab = (float*)stg(2);           // [128][4][2] = 4 KB
    float* mtab = (float*)stg(2) + 1024;    // [128][2]

    float bc[4], gc[4], bec[4];
#pragma unroll
    for (int ni = 0; ni < 4; ni++) {
      int col = wn * 64 + ni * 16 + cl;
      bc[ni] = b_out[col]; gc[ni] = g0[col]; bec[ni] = be0[col];
    }
#pragma unroll
    for (int mi = 0; mi < 4; mi++) {
#pragma unroll
      for (int ni = 0; ni < 4; ni++) {
        int col = wn * 64 + ni * 16 + cl;
#pragma unroll
        for (int r = 0; r < 4; r++) {
          int row = wm * 64 + mi * 16 + g4 * 4 + r;
          int qrow = m0 + row; qrow = (qrow < M) ? qrow : (M - 1);
          accF[mi][ni][r] += bc[ni] + query[(size_t)qrow * 256 + col];
        }
      }
    }
#pragma unroll
    for (int mi = 0; mi < 4; mi++) {
#pragma unroll
      for (int r = 0; r < 4; r++) {
        float s = accF[mi][0][r] + accF[mi][1][r] + accF[mi][2][r] + accF[mi][3][r];
        float sq = accF[mi][0][r] * accF[mi][0][r] + accF[mi][1][r] * accF[mi][1][r] +
                   accF[mi][2][r] * accF[mi][2][r] + accF[mi][3][r] * accF[mi][3][r];
#pragma unroll
        for (int o = 1; o < 16; o <<= 1) {
          s += __shfl_xor(s, o, 64);
          sq += __shfl_xor(sq, o, 64);
        }
        if (cl == 0) {
          int row = wm * 64 + mi * 16 + g4 * 4 + r;
          ptab[(row * 4 + wn) * 2 + 0] = s;
          ptab[(row * 4 + wn) * 2 + 1] = sq;
        }
      }
    }
    __syncthreads();
    {
      int row = t >> 2, part = t & 3;
      float s = ptab[(row * 4 + part) * 2 + 0];
      float sq = ptab[(row * 4 + part) * 2 + 1];
      s += __shfl_xor(s, 1, 64);  sq += __shfl_xor(sq, 1, 64);
      s += __shfl_xor(s, 2, 64);  sq += __shfl_xor(sq, 2, 64);
      if (part == 0) {
        float mean = s * (1.f / 256.f);
        float var = sq * (1.f / 256.f) - mean * mean;
        mtab[row * 2 + 0] = mean;
        mtab[row * 2 + 1] = rsqrtf(var + 1e-5f);
      }
    }
    __syncthreads();
    // x -> As in ffn frag order [s 0..31][row 0..127][8] (samp is dead)
#pragma unroll
    for (int mi = 0; mi < 4; mi++) {
#pragma unroll
      for (int r = 0; r < 4; r++) {
        int row = wm * 64 + mi * 16 + g4 * 4 + r;
        float2 ms = *reinterpret_cast<const float2*>(mtab + row * 2);
#pragma unroll
        for (int ni = 0; ni < 4; ni++) {
          int col = wn * 64 + ni * 16 + cl;
          As[(col >> 3) * 1024 + row * 8 + (col & 7)] =
              f32_to_bf16((accF[mi][ni][r] - ms.x) * ms.y * gc[ni] + bec[ni]);
        }
      }
    }
    // reset accF for phase 2
#pragma unroll
    for (int mi = 0; mi < 4; mi++)
#pragma unroll
      for (int ni = 0; ni < 4; ni++)
        accF[mi][ni] = (f32x4){0.f, 0.f, 0.f, 0.f};
    __syncthreads();
  }

  // ================= PHASE 2: FFN + LN1 (R16 ffn loop) =================
  auto issueB1 = [&](int p, int j, ushort* dst) {
    const ushort* src = w1f + (size_t)(p * 4 + j) * 8192;
#pragma unroll
    for (int ii = 0; ii < 2; ++ii) {
      int c = t + 512 * ii;
      __builtin_amdgcn_global_load_lds(
          (const __attribute__((address_space(1))) void*)(src + (size_t)c * 8),
          (__attribute__((address_space(3))) void*)(dst + (size_t)c * 8), 16, 0, 0);
    }
  };
  auto issueB2 = [&](int p, int tt, ushort* dst) {
    const ushort* src = w2f + (size_t)(p * 4 + tt) * 8192;
#pragma unroll
    for (int ii = 0; ii < 2; ++ii) {
      int c = t + 512 * ii;
      __builtin_amdgcn_global_load_lds(
          (const __attribute__((address_space(1))) void*)(src + (size_t)c * 8),
          (__attribute__((address_space(3))) void*)(dst + (size_t)c * 8), 16, 0, 0);
    }
  };

  issueB1(0, 0, stg(0));
  issueB1(0, 1, stg(1));
  asm volatile("s_waitcnt vmcnt(2)" ::: "memory");  // stage0 done, stage1 in flight
  __builtin_amdgcn_s_barrier();

  f32x4 acc1[4][2] = {};
  int cur = 0;

  for (int p = 0; p < 16; ++p) {
#pragma unroll
    for (int j = 0; j < 8; ++j) {
      int tgt = cur + 2; if (tgt >= 3) tgt -= 3;
      if (j <= 5) {
        const int j2 = j + 2;
        const int p2 = p + (j2 >> 3);
        if ((j2 & 7) < 4) issueB1(p2, j2 & 3, stg(tgt));
        else issueB2(p2, (j2 & 7) - 4, stg(tgt));
        asm volatile("s_waitcnt vmcnt(4) lgkmcnt(0)" ::: "memory");
      } else if (p < 15) {
        const int j2m = (j + 2) & 7;
        issueB1(p + 1, j2m, stg(tgt));
        asm volatile("s_waitcnt vmcnt(4) lgkmcnt(0)" ::: "memory");
      } else if (j == 6) {
        asm volatile("s_waitcnt vmcnt(2) lgkmcnt(0)" ::: "memory");
      } else {
        asm volatile("s_waitcnt vmcnt(0) lgkmcnt(0)" ::: "memory");
      }
      __builtin_amdgcn_s_barrier();
      __builtin_amdgcn_sched_barrier(0);

      const ushort* Bs = stg(cur);
      if (j < 4) {
        __builtin_amdgcn_s_setprio(1);
#pragma unroll
        for (int kk = 0; kk < 2; ++kk) {
          bf16x8 afr[4], bfr[2];
          const int slotA = j * 8 + kk * 4 + kq;
#pragma unroll
          for (int mi = 0; mi < 4; mi++)
            afr[mi] = *reinterpret_cast<const bf16x8*>(
                As + slotA * 1024 + (wm * 64 + mi * 16 + rl) * 8);
          const int slotB = kk * 4 + kq;
#pragma unroll
          for (int ni = 0; ni < 2; ni++)
            bfr[ni] = *reinterpret_cast<const bf16x8*>(
                Bs + slotB * 1024 + (wn * 32 + ni * 16 + rl) * 8);
#pragma unroll
          for (int mi = 0; mi < 4; mi++)
#pragma unroll
            for (int ni = 0; ni < 2; ni++)
              acc1[mi][ni] = __builtin_amdgcn_mfma_f32_16x16x32_bf16(afr[mi], bfr[ni], acc1[mi][ni], 0, 0, 0);
        }
        __builtin_amdgcn_s_setprio(0);
        if (j == 3) {
#pragma unroll
          for (int ni = 0; ni < 2; ni++) {
            int col = wn * 32 + ni * 16 + cl;
            float b1v = b1[p * 128 + col];
            const int s = col >> 3, w8 = col & 7;
#pragma unroll
            for (int mi = 0; mi < 4; mi++) {
#pragma unroll
              for (int r = 0; r < 4; r++) {
                int row = wm * 64 + mi * 16 + g4 * 4 + r;
                Hs[s * 1032 + row * 8 + w8] = f32_to_bf16(fmaxf(acc1[mi][ni][r] + b1v, 0.f));
              }
            }
          }
#pragma unroll
          for (int mi = 0; mi < 4; mi++)
#pragma unroll
            for (int ni = 0; ni < 2; ni++)
              acc1[mi][ni] = (f32x4){0.f, 0.f, 0.f, 0.f};
        }
      } else {
        const int tt = j - 4;
        bf16x8 a2f[4], b2f[4];
#pragma unroll
        for (int mi = 0; mi < 4; mi++)
          a2f[mi] = *reinterpret_cast<const bf16x8*>(
              Hs + (tt * 4 + kq) * 1032 + (wm * 64 + mi * 16 + rl) * 8);
#pragma unroll
        for (int ni = 0; ni < 4; ni++)
          b2f[ni] = *reinterpret_cast<const bf16x8*>(
              Bs + kq * 2048 + (wn * 64 + ni * 16 + rl) * 8);
        __builtin_amdgcn_s_setprio(1);
#pragma unroll
        for (int mi = 0; mi < 4; mi++)
#pragma unroll
          for (int ni = 0; ni < 4; ni++)
            accF[mi][ni] = __builtin_amdgcn_mfma_f32_16x16x32_bf16(a2f[mi], b2f[ni], accF[mi][ni], 0, 0, 0);
        __builtin_amdgcn_s_setprio(0);
      }
      cur = cur + 1; if (cur >= 3) cur -= 3;
    }
  }

  // ---- LN1 epilogue ----
  float* ptab = (float*)stg0;
  float* mtab = (float*)(stg0 + 2048);

  float b2c[4], g1c[4], bec[4];
#pragma unroll
  for (int ni = 0; ni < 4; ni++) {
    int col = wn * 64 + ni * 16 + cl;
    b2c[ni] = b2[col]; g1c[ni] = g1[col]; bec[ni] = be1[col];
  }
#pragma unroll
  for (int mi = 0; mi < 4; mi++) {
#pragma unroll
    for (int ni = 0; ni < 4; ni++) {
      int col = wn * 64 + ni * 16 + cl;
#pragma unroll
      for (int r = 0; r < 4; r++) {
        int row = wm * 64 + mi * 16 + g4 * 4 + r;
        ushort xv = As[(col >> 3) * 1024 + row * 8 + (col & 7)];
        accF[mi][ni][r] += b2c[ni] + bf16_to_f32(xv);
      }
    }
  }
#pragma unroll
  for (int mi = 0; mi < 4; mi++) {
#pragma unroll
    for (int r = 0; r < 4; r++) {
      float s = accF[mi][0][r] + accF[mi][1][r] + accF[mi][2][r] + accF[mi][3][r];
      float sq = accF[mi][0][r] * accF[mi][0][r] + accF[mi][1][r] * accF[mi][1][r] +
                 accF[mi][2][r] * accF[mi][2][r] + accF[mi][3][r] * accF[mi][3][r];
#pragma unroll
      for (int o = 1; o < 16; o <<= 1) {
        s += __shfl_xor(s, o, 64);
        sq += __shfl_xor(sq, o, 64);
      }
      if (cl == 0) {
        int row = wm * 64 + mi * 16 + g4 * 4 + r;
        ptab[(row * 4 + wn) * 2 + 0] = s;
        ptab[(row * 4 + wn) * 2 + 1] = sq;
      }
    }
  }
  __syncthreads();
  {
    int row = t >> 2, part = t & 3;
    float s = ptab[(row * 4 + part) * 2 + 0];
    float sq = ptab[(row * 4 + part) * 2 + 1];
    s += __shfl_xor(s, 1, 64);  sq += __shfl_xor(sq, 1, 64);
    s += __shfl_xor(s, 2, 64);  sq += __shfl_xor(sq, 2, 64);
    if (part == 0) {
      float mean = s * (1.f / 256.f);
      float var = sq * (1.f / 256.f) - mean * mean;
      mtab[row * 2 + 0] = mean;
      mtab[row * 2 + 1] = rsqrtf(var + 1e-5f);
    }
  }
  __syncthreads();
#pragma unroll
  for (int mi = 0; mi < 4; mi++) {
#pragma unroll
    for (int r = 0; r < 4; r++) {
      int row = wm * 64 + mi * 16 + g4 * 4 + r;
      float2 ms = *reinterpret_cast<const float2*>(mtab + row * 2);
      int grow = m0 + row;
      if (grow < M) {
#pragma unroll
        for (int ni = 0; ni < 4; ni++) {
          int col = wn * 64 + ni * 16 + cl;
          out[(size_t)grow * 256 + col] = (accF[mi][ni][r] - ms.x) * ms.y * g1c[ni] + bec[ni];
        }
      }
    }
  }
}

// ---------------- deformable attention sampling ----------------------------
__global__ __launch_bounds__(256) void deform_attn_kernel(
    const ushort* __restrict__ val,  // [R][256] bf16
    const ushort* __restrict__ oa,   // [R][192] bf16: off 0..127 | aw 128..191
    const float* __restrict__ refp,  // [R][4]
    ushort* __restrict__ out,        // frag-order, 16384 us per 64-row block
    int R) {
  __shared__ ushort repack[2048];    // [s 0..31][rloc 0..7][8]

  const int t = threadIdx.x;
  const int c = t & 3;
  const int h = (t >> 2) & 7;
  const int rloc = t >> 5;
  const int row0 = blockIdx.x * 8;
  const int row = row0 + rloc;

  if (row < R) {
    const int bl = row / NQv;
    const ushort* orow = oa + (size_t)row * 192;

    uint lraw = *reinterpret_cast<const uint*>(orow + 128 + h * 8 + c * 2);
    float l0 = bf16_to_f32((ushort)(lraw & 0xffffu));
    float l1 = bf16_to_f32((ushort)(lraw >> 16));
    float mx = fmaxf(l0, l1);
    mx = fmaxf(mx, __shfl_xor(mx, 1, 64));
    mx = fmaxf(mx, __shfl_xor(mx, 2, 64));
    float e0 = __expf(l0 - mx), e1 = __expf(l1 - mx);
    float sm = e0 + e1;
    sm += __shfl_xor(sm, 1, 64);
    sm += __shfl_xor(sm, 2, 64);
    float inv = 1.f / sm;

    ushort o4[4];
    *reinterpret_cast<uint2*>(o4) = *reinterpret_cast<const uint2*>(orow + h * 16 + c * 4);
    float4 rp = *reinterpret_cast<const float4*>(refp + (size_t)row * 4);
    float Wl = (c & 2) ? 50.f : 100.f;
    float fx = ((c & 2) ? rp.z : rp.x) * Wl - 0.5f;
    float fy = ((c & 2) ? rp.w : rp.y) * Wl - 0.5f;
    float myx0 = fx + bf16_to_f32(o4[0]);
    float myy0 = fy + bf16_to_f32(o4[1]);
    float myx1 = fx + bf16_to_f32(o4[2]);
    float myy1 = fy + bf16_to_f32(o4[3]);
    float myw0 = e0 * inv, myw1 = e1 * inv;

    const int lanebase = (t & 63) & ~3;
    float acc8[8] = {};
#pragma unroll
    for (int p = 0; p < 8; ++p) {
      const int src = lanebase | (p >> 1);
      float x = __shfl((p & 1) ? myx1 : myx0, src, 64);
      float y = __shfl((p & 1) ? myy1 : myy0, src, 64);
      float w = __shfl((p & 1) ? myw1 : myw0, src, 64);
      const int W = (p < 4) ? 100 : 50, H = W;
      const ushort* vbase = val + ((size_t)bl * NQv + ((p < 4) ? 0 : 10000)) * 256 + h * 32 + c * 8;
      float x0f = floorf(x), y0f = floorf(y);
      float wx1 = x - x0f, wy1 = y - y0f;
      float wx0 = 1.f - wx1, wy0 = 1.f - wy1;
      int x0 = (int)x0f, y0 = (int)y0f;
      float cw[4] = {w * wx0 * wy0, w * wx1 * wy0, w * wx0 * wy1, w * wx1 * wy1};
      int cx[4] = {x0, x0 + 1, x0, x0 + 1};
      int cy[4] = {y0, y0, y0 + 1, y0 + 1};
#pragma unroll
      for (int cc = 0; cc < 4; cc++) {
        int xi = cx[cc], yi = cy[cc];
        if (xi >= 0 && xi < W && yi >= 0 && yi < H) {
          ushort vr[8];
          *reinterpret_cast<uint4*>(vr) =
              *reinterpret_cast<const uint4*>(vbase + (size_t)(yi * W + xi) * 256);
          float ww = cw[cc];
#pragma unroll
          for (int j = 0; j < 8; j++) acc8[j] += ww * bf16_to_f32(vr[j]);
        }
      }
    }

    ushort st[8];
#pragma unroll
    for (int j = 0; j < 8; j++) st[j] = f32_to_bf16(acc8[j]);
    *reinterpret_cast<uint4*>(repack + (size_t)(h * 4 + c) * 64 + (size_t)rloc * 8) =
        *reinterpret_cast<uint4*>(st);
  }
  __syncthreads();

  {
    int s2 = t >> 3, r2 = t & 7;
    int grow = row0 + r2;
    if (grow < R) {
      int b64 = row0 >> 6, inner = (row0 & 63) + r2;
      *reinterpret_cast<uint4*>(out + (size_t)b64 * 16384 + (size_t)s2 * 512 + (size_t)inner * 8) =
          *reinterpret_cast<const uint4*>(repack + (size_t)s2 * 64 + (size_t)r2 * 8);
    }
  }
}

// ---------------------------------------------------------------------------
extern "C" void kernel_launch(void* const* d_in, const int* in_sizes, int n_in,
                              void* d_out, int out_size, void* d_ws, size_t ws_size,
                              hipStream_t stream) {
  const float* query  = (const float*)d_in[0];
  const float* refp   = (const float*)d_in[1];
  const float* w_off  = (const float*)d_in[2];
  const float* b_off  = (const float*)d_in[3];
  const float* w_attn = (const float*)d_in[4];
  const float* b_attn = (const float*)d_in[5];
  const float* w_val  = (const float*)d_in[6];
  const float* b_val  = (const float*)d_in[7];
  const float* w_out  = (const float*)d_in[8];
  const float* b_out  = (const float*)d_in[9];
  const float* w1     = (const float*)d_in[10];
  const float* b1     = (const float*)d_in[11];
  const float* w2     = (const float*)d_in[12];
  const float* b2     = (const float*)d_in[13];
  const float* ln0g   = (const float*)d_in[14];
  const float* ln0b   = (const float*)d_in[15];
  const float* ln1g   = (const float*)d_in[16];
  const float* ln1b   = (const float*)d_in[17];
  float* outp = (float*)d_out;

  char* ws = (char*)d_ws;
  size_t woff = 0;
  auto walloc = [&](size_t bytes) { size_t r = woff; woff += (bytes + 255) & ~(size_t)255; return r; };
  ushort* wcat = (ushort*)(ws + walloc((size_t)512 * 256 * 2));
  float*  bcat = (float*)(ws + walloc(512 * 4));
  ushort* wqf  = (ushort*)(ws + walloc((size_t)8 * 8192 * 2));
  ushort* w1f  = (ushort*)(ws + walloc((size_t)64 * 8192 * 2));
  ushort* w2f  = (ushort*)(ws + walloc((size_t)64 * 8192 * 2));
  char* arena = ws + woff;
  size_t arena_sz = (ws_size > woff) ? (ws_size - woff) : 0;

  int nb = ((size_t)BSv * NQv * 1920 + (4u << 20) <= arena_sz) ? BSv : 1;
  const int R = nb * NQv;
  const size_t smsz = (size_t)((R + 127) / 128) * 65536;   // samp bytes (pad to 128 rows)
  ushort* qb   = (ushort*)arena;
  ushort* valb = (ushort*)(arena + (size_t)R * 512);
  ushort* oab  = (ushort*)(arena + (size_t)R * 1024);
  ushort* samp = (ushort*)(arena + (size_t)R * 1408);

  build_wcat_kernel<<<dim3(448), dim3(256), 0, stream>>>(
      w_val, w_off, w_attn, b_val, b_off, b_attn, wcat, bcat);
  ttrans_stage_kernel<2><<<dim3(4, 4), dim3(256), 0, stream>>>(w_out, wqf, 256);
  ttrans_stage_kernel<0><<<dim3(32, 4), dim3(256), 0, stream>>>(w1, w1f, 2048);
  ttrans_stage_kernel<1><<<dim3(4, 32), dim3(256), 0, stream>>>(w2, w2f, 256);

  const int MT = (R + TBM - 1) / TBM;
  (void)smsz;

  for (int c = 0; c < BSv / nb; c++) {
    const int row0 = c * R;
    const float* qrow = query + (size_t)row0 * Dv;

    conv_bf16_kernel<<<dim3((R * 64 + 255) / 256), dim3(256), 0, stream>>>(qrow, qb, R * 64);

    gemm128_kernel<0, 1, 1><<<dim3(4, MT), dim3(256), 0, stream>>>(
        qb, wcat, bcat, valb, oab, R, Dv, 448, 448);

    deform_attn_kernel<<<dim3((R + 7) / 8), dim3(256), 0, stream>>>(
        valb, oab, refp + (size_t)row0 * 4, samp, R);

    attnout_ffn_kernel<<<dim3((R + 127) / 128), dim3(512), 0, stream>>>(
        samp, wqf, b_out, qrow, ln0g, ln0b, w1f, b1, w2f, b2, ln1g, ln1b,
        outp + (size_t)row0 * 256, R);
  }
}